// Round 7
// baseline (247.103 us; speedup 1.0000x reference)
//
#include <hip/hip_runtime.h>
#include <hip/hip_fp16.h>

#define NN 50000
#define NE 800000
#define GB0 782       // gemm blocks in gemm0_k
#define NBLK1 391     // scatter blocks, 2048 edges each
#define NBUCK 196     // coarse buckets = dst>>8
#define BCAP 8192     // per-bucket staging capacity (mean 4096, sigma 64 -> 64-sigma margin)
#define NSHARD 16     // BN-stat partial shards

typedef __attribute__((ext_vector_type(8))) short bf16x8;
typedef __attribute__((ext_vector_type(4))) float f32x4;
typedef __attribute__((ext_vector_type(2))) float f32x2;

__device__ inline float blo(unsigned u) { union { unsigned i; float f; } c; c.i = u << 16; return c.f; }
__device__ inline float bhi(unsigned u) { union { unsigned i; float f; } c; c.i = u & 0xFFFF0000u; return c.f; }
__device__ inline unsigned short f2b(float f) {
    union { float f; unsigned u; } c; c.f = f;
    return (unsigned short)((c.u + 0x7FFFu + ((c.u >> 16) & 1u)) >> 16);
}
// 2 fp32 -> packed 2xbf16, RNE. NOTE: v_cvt_pk_bf16_f32 is NOT RNE on gfx950
// (R4 failure: absmax 1.75 -> 4.25). Keep the integer RNE sequence.
__device__ inline unsigned pack2(float x, float y) {
    union { float f; unsigned u; } a, b; a.f = x; b.f = y;
    const unsigned lo = (a.u + 0x7FFFu + ((a.u >> 16) & 1u)) >> 16;
    const unsigned hi = (b.u + 0x7FFFu + ((b.u >> 16) & 1u)) & 0xFFFF0000u;
    return (lo & 0xFFFFu) | hi;
}
__device__ inline float edgew(unsigned u) {
    return __half2float(__ushort_as_half((unsigned short)(u >> 16)));
}
__device__ inline bf16x8 u4_to_b8(unsigned a, unsigned b, unsigned c, unsigned d) {
    union { unsigned u[4]; bf16x8 v; } x;
    x.u[0] = a; x.u[1] = b; x.u[2] = c; x.u[3] = d;
    return x.v;
}
// pack 4 fp32 -> 4 fp8 e4m3 (one uint)
__device__ inline unsigned pk_fp8x4(float a, float b, float c, float d) {
    int t = 0;
    t = __builtin_amdgcn_cvt_pk_fp8_f32(a, b, t, false);
    t = __builtin_amdgcn_cvt_pk_fp8_f32(c, d, t, true);
    return (unsigned)t;
}

// ================= weight packing =================
__device__ __forceinline__ void packb_body(const float* __restrict__ B, short* __restrict__ Bp, int NT, int b)
{
    const int o = b * 256 + threadIdx.x;
    if (o >= 4096 * NT) return;
    const int j = o & 7;
    const int lane = (o >> 3) & 63;
    const int tnt = o >> 9;
    const int nt = tnt % NT, ks = tnt / NT;
    const int k = ks * 32 + (lane >> 4) * 8 + j;
    const int n = nt * 16 + (lane & 15);
    Bp[o] = (short)f2b(B[k * (NT * 16) + n]);
}

// fused: W0 packing + zero-init of BN-stat shards and bucket counters
__global__ __launch_bounds__(256) void packb0_k(const float* __restrict__ W0, short* __restrict__ Bp0,
                                                float* __restrict__ stz)
{
    const int o = blockIdx.x * 256 + threadIdx.x;
    if (o < 8448) stz[o] = 0.f;   // 8192 stat shards + 256 bucket counters
    packb_body(W0, Bp0, 8, blockIdx.x);
}

// ================= MFMA GEMM body =================
// MODE 0: A = fp32 [M,256], split-K staged: two 64x128 half-tiles -> swizzled bf16 LDS (16KB)
// MODE 1: A = x1p pre-only [M,64] uints, per-lane direct loads (frag used twice)
// FP8OUT: C is fp8 e4m3 [M, NT*16] bytes; else bf16 [M, NT*16] shorts
// MODE 1: sum/ss point to NSHARD x 128 partial arrays (reduced in preamble)
template <int NT, int MODE, bool FP8OUT>
__device__ __forceinline__ void gemm_body(
    const void* __restrict__ Av, const short* __restrict__ Bp,
    void* __restrict__ Cv, int M,
    const float* __restrict__ sum, const float* __restrict__ ss,
    const float* __restrict__ gam, const float* __restrict__ bet)
{
    constexpr int TC = (NT > 4) ? 4 : NT;
    constexpr int NCC = TC * 16;
    constexpr int CLB = 4 * 16 * NCC * 4;                       // Cl bytes
    constexpr int SMB = (MODE == 0 && 16384 > CLB) ? 16384 : CLB;
    // smem: MODE 0 = A half-tile (64x64 uints, swizzled) aliased with Cl; else Cl only
    __shared__ __align__(16) unsigned char smem[SMB];
    unsigned* As = (unsigned*)smem;
    __shared__ float scs[128], shs[128];
    const int tid = threadIdx.x;
    const int w = tid >> 6;
    const int lane = tid & 63;
    const int lane15 = lane & 15;
    const int quad = lane >> 4;
    const int row0 = blockIdx.x * 64;
    const int m = row0 + w * 16 + lane15;
    const int mc = (m < M) ? m : 0;

    if (MODE == 1) {
        if (tid < 128) {
            float s = 0.f, q = 0.f;
#pragma unroll
            for (int i = 0; i < NSHARD; ++i) {
                s += sum[i * 128 + tid];
                q += ss[i * 128 + tid];
            }
            const float inv = 1.f / (float)M;
            const float mu = s * inv;
            const float var = q * inv - mu * mu;
            const float sc = gam[tid] * rsqrtf(var + 1e-5f);
            scs[tid] = sc;
            shs[tid] = bet[tid] - mu * sc;
        }
        __syncthreads();
    }

    f32x4 acc[NT];
#pragma unroll
    for (int t = 0; t < NT; ++t) acc[t] = (f32x4){0.f, 0.f, 0.f, 0.f};

    if (MODE == 0) {
        // ---- split-K coalesced stage: 2 halves of 64 rows x 128 fp32 -> bf16x2 LDS ----
        const float* xb = (const float*)Av + (long)row0 * 256;
        const int rlim = M - row0;
        const int ml = w * 16 + lane15;
#pragma unroll
        for (int kh = 0; kh < 2; ++kh) {
            if (kh) __syncthreads();          // all waves done reading previous half
#pragma unroll
            for (int it = 0; it < 4; ++it) {
                const int o = it * 256 + tid;        // 0..1023
                const int r = o >> 4;                // local row 0..63
                const int cc = o & 15;               // 8-float chunk within half-row
                float4 v0 = make_float4(0.f, 0.f, 0.f, 0.f);
                float4 v1 = make_float4(0.f, 0.f, 0.f, 0.f);
                if (r < rlim) {
                    v0 = *(const float4*)&xb[r * 256 + kh * 128 + cc * 8];
                    v1 = *(const float4*)&xb[r * 256 + kh * 128 + cc * 8 + 4];
                }
                *(uint4*)&As[r * 64 + ((cc * 4) ^ ((r & 7) << 2))] =
                    make_uint4(pack2(v0.x, v0.y), pack2(v0.z, v0.w),
                               pack2(v1.x, v1.y), pack2(v1.z, v1.w));
            }
            __syncthreads();
#pragma unroll
            for (int ks4 = 0; ks4 < 4; ++ks4) {
                const int ks = kh * 4 + ks4;
                const bf16x8 af = *(const bf16x8*)&As[ml * 64 + ((ks4 * 16 + quad * 4) ^ ((ml & 7) << 2))];
#pragma unroll
                for (int t = 0; t < NT; ++t) {
                    const bf16x8 bf = *(const bf16x8*)&Bp[(((ks * NT + t) * 64) + lane) * 8];
                    acc[t] = __builtin_amdgcn_mfma_f32_16x16x32_bf16(af, bf, acc[t], 0, 0, 0);
                }
            }
        }
        __syncthreads();   // hand-off: As region reused as Cl below
    } else {
        const unsigned* arow = (const unsigned*)Av + (long)mc * 64;
#pragma unroll
        for (int ks = 0; ks < 4; ++ks) {
            const uint4 pv = *(const uint4*)&arow[ks * 16 + quad * 4];
            const bf16x8 apre = u4_to_b8(pv.x, pv.y, pv.z, pv.w);
            const int c0 = ks * 32 + quad * 8;
            const float4 s0 = *(const float4*)&scs[c0];
            const float4 s1 = *(const float4*)&scs[c0 + 4];
            const float4 h0 = *(const float4*)&shs[c0];
            const float4 h1 = *(const float4*)&shs[c0 + 4];
            const bf16x8 aact = u4_to_b8(
                pack2(fmaxf(fmaf(blo(pv.x), s0.x, h0.x), 0.f), fmaxf(fmaf(bhi(pv.x), s0.y, h0.y), 0.f)),
                pack2(fmaxf(fmaf(blo(pv.y), s0.z, h0.z), 0.f), fmaxf(fmaf(bhi(pv.y), s0.w, h0.w), 0.f)),
                pack2(fmaxf(fmaf(blo(pv.z), s1.x, h1.x), 0.f), fmaxf(fmaf(bhi(pv.z), s1.y, h1.y), 0.f)),
                pack2(fmaxf(fmaf(blo(pv.w), s1.z, h1.z), 0.f), fmaxf(fmaf(bhi(pv.w), s1.w, h1.w), 0.f)));
#pragma unroll
            for (int t = 0; t < NT; ++t) {
                const bf16x8 bf = *(const bf16x8*)&Bp[(((ks * NT + t) * 64) + lane) * 8];
                acc[t] = __builtin_amdgcn_mfma_f32_16x16x32_bf16(aact, bf, acc[t], 0, 0, 0);
            }
#pragma unroll
            for (int t = 0; t < NT; ++t) {
                const bf16x8 bf = *(const bf16x8*)&Bp[((((ks + 4) * NT + t) * 64) + lane) * 8];
                acc[t] = __builtin_amdgcn_mfma_f32_16x16x32_bf16(apre, bf, acc[t], 0, 0, 0);
            }
        }
    }

    // per-wave chunked epilogue: LDS transpose -> pack -> vector stores
    float* cl = (float*)smem + w * 16 * NCC;
#pragma unroll
    for (int t0 = 0; t0 < NT; t0 += TC) {
#pragma unroll
        for (int tt = 0; tt < TC; ++tt)
#pragma unroll
            for (int r = 0; r < 4; ++r)
                cl[(quad * 4 + r) * NCC + tt * 16 + lane15] = acc[t0 + tt][r];
        if (FP8OUT) {
            constexpr int BPL = NCC / 4;     // fp8 bytes per lane
            const int f = lane * BPL;
            const int r = f / NCC;
            const int col = f % NCC;
            const int grow = row0 + w * 16 + r;
            unsigned ou[BPL / 4];
#pragma unroll
            for (int q = 0; q < BPL / 4; ++q) {
                const float4 v = *(const float4*)&cl[f + q * 4];
                ou[q] = pk_fp8x4(v.x, v.y, v.z, v.w);
            }
            if (grow < M) {
                unsigned char* cp = (unsigned char*)Cv + (long)grow * (NT * 16) + t0 * 16 + col;
                if (BPL == 16) *(uint4*)cp = make_uint4(ou[0], ou[1], ou[2], ou[3]);
                else           *(uint2*)cp = make_uint2(ou[0], ou[1]);
            }
        } else {
#pragma unroll
            for (int i = 0; i < (16 * NCC) / 512; ++i) {
                const int f = i * 512 + lane * 8;
                const int r = f / NCC;
                const int col = f % NCC;
                const int grow = row0 + w * 16 + r;
                const float4 lo = *(const float4*)&cl[f];
                const float4 hi = *(const float4*)&cl[f + 4];
                uint4 o;
                o.x = pack2(lo.x, lo.y);
                o.y = pack2(lo.z, lo.w);
                o.z = pack2(hi.x, hi.y);
                o.w = pack2(hi.z, hi.w);
                if (grow < M) *(uint4*)((short*)Cv + (long)grow * (NT * 16) + t0 * 16 + col) = o;
            }
        }
    }
}

// scatter body: per-block LDS hist -> atomic bucket-range reservation -> scatter
// into fixed-capacity bucket regions (no cross-block scan dependency).
__device__ __forceinline__ void scatter_body(
    int k, const int* __restrict__ src, const int* __restrict__ dst, const float* __restrict__ ew,
    int* __restrict__ bcnt, unsigned* __restrict__ ebA, unsigned char* __restrict__ ebB)
{
    __shared__ int cnt[256];
    __shared__ int myoff[256];
    const int t = threadIdx.x;
    cnt[t] = 0;
    __syncthreads();
    const int ebase = k * 2048;
    int d[8];
#pragma unroll
    for (int i = 0; i < 8; ++i) {
        const int e = ebase + i * 256 + t;
        if (e < NE) { d[i] = dst[e]; atomicAdd(&cnt[(unsigned)d[i] >> 8], 1); }
        else d[i] = -1;
    }
    __syncthreads();
    if (t < NBUCK && cnt[t] > 0)
        myoff[t] = t * BCAP + atomicAdd(&bcnt[t], cnt[t]);
    __syncthreads();
#pragma unroll
    for (int i = 0; i < 8; ++i) {
        const int e = ebase + i * 256 + t;
        if (e < NE) {
            const int dd = d[i];
            const int pos = atomicAdd(&myoff[(unsigned)dd >> 8], 1);
            const unsigned wb = (unsigned)__half_as_ushort(__float2half_rn(ew[e]));
            ebA[pos] = ((unsigned)src[e] & 0xFFFFu) | (wb << 16);
            ebB[pos] = (unsigned char)(dd & 255);
        }
    }
}

// layer-0 GEMM (fp8 C) + W1/W2 packing
__global__ __launch_bounds__(256) void gemm0_k(
    const float* __restrict__ x, const short* __restrict__ Bp, unsigned char* __restrict__ C, int M,
    const float* __restrict__ W1, const float* __restrict__ W2,
    short* __restrict__ Bp1, short* __restrict__ Bp2)
{
    if (blockIdx.x < GB0) {
        gemm_body<8, 0, true>(x, Bp, C, M, nullptr, nullptr, nullptr, nullptr);
    } else if (blockIdx.x < GB0 + 128) {
        packb_body(W1, Bp1, 8, blockIdx.x - GB0);
    } else {
        packb_body(W2, Bp2, 2, blockIdx.x - (GB0 + 128));
    }
}

// standalone edge scatter (separate launch for rocprof attribution)
__global__ __launch_bounds__(256) void scatter_k(
    const int* __restrict__ src, const int* __restrict__ dst, const float* __restrict__ ew,
    int* __restrict__ bcnt, unsigned* __restrict__ ebA, unsigned char* __restrict__ ebB)
{
    scatter_body(blockIdx.x, src, dst, ew, bcnt, ebA, ebB);
}

// phase2: per bucket (staged at b*BCAP, count bcnt[b]): count -> scan -> rs + compact pe
__global__ __launch_bounds__(256) void phase2_k(
    const unsigned* __restrict__ ebA, const unsigned char* __restrict__ ebB,
    const int* __restrict__ bcnt, int* __restrict__ rs, unsigned* __restrict__ pe)
{
    __shared__ int bscan[256];
    __shared__ int cnt[256];
    __shared__ int cur[256];
    const int b = blockIdx.x;
    const int t = threadIdx.x;
    const int v0 = (t < NBUCK) ? bcnt[t] : 0;
    bscan[t] = v0;
    __syncthreads();
    for (int off = 1; off < 256; off <<= 1) {
        const int x = (t >= off) ? bscan[t - off] : 0;
        __syncthreads();
        bscan[t] += x;
        __syncthreads();
    }
    const int nb = bcnt[b];
    const int e1 = bscan[b];      // compact end
    const int e0 = e1 - nb;       // compact start
    const int i0 = b * BCAP;      // staged start
    cnt[t] = 0;
    __syncthreads();
    for (int i = t; i < nb; i += 256) atomicAdd(&cnt[ebB[i0 + i]], 1);
    __syncthreads();
    const int v = cnt[t];
    __syncthreads();
    for (int off = 1; off < 256; off <<= 1) {
        const int x = (t >= off) ? cnt[t - off] : 0;
        __syncthreads();
        cnt[t] += x;
        __syncthreads();
    }
    const int exc = cnt[t] - v;
    const int node = b * 256 + t;
    if (node < NN) rs[node] = e0 + exc;
    if (b == 0 && t == 0) rs[NN] = NE;
    cur[t] = e0 + exc;
    __syncthreads();
    for (int i = t; i < nb; i += 256) {
        const int e = i0 + i;
        const int pos = atomicAdd(&cur[ebB[e]], 1);
        pe[pos] = ebA[e];
    }
}

template <int NT, bool F8>
__global__ __launch_bounds__(256) void gemm_bn(
    const unsigned* __restrict__ A, const short* __restrict__ Bp, void* __restrict__ C, int M,
    const float* __restrict__ sum, const float* __restrict__ ss,
    const float* __restrict__ gam, const float* __restrict__ bet)
{
    gemm_body<NT, 1, F8>(A, Bp, C, M, sum, ss, gam, bet);
}

// BN-stat epilogue shared by agg kernels: each thread holds 4 channel values (ch 4l..4l+3)
// of one node-slot; LDS-reduce 8 nodes/block, atomicAdd into sharded partials.
__device__ __forceinline__ void bnstat_epi(
    float* __restrict__ SL, float c0, float c1, float c2, float c3,
    float* __restrict__ sumP, float* __restrict__ ssP)
{
    const int slot = threadIdx.x >> 5;
    const int l = threadIdx.x & 31;
    *(float4*)&SL[slot * 128 + l * 4] = make_float4(c0, c1, c2, c3);
    __syncthreads();
    if (threadIdx.x < 128) {
        float s = 0.f, q = 0.f;
#pragma unroll
        for (int i = 0; i < 8; ++i) {
            const float x = SL[i * 128 + threadIdx.x];
            s += x;
            q = fmaf(x, x, q);
        }
        const int sh = (blockIdx.x & (NSHARD - 1)) * 128 + threadIdx.x;
        atomicAdd(&sumP[sh], s);
        atomicAdd(&ssP[sh], q);
    }
}

// ================= aggregation (layers 0 and 1): fp8 h rows (128 B) + fused BN stats =================
// 2 nodes/wave, 32 lanes/node; lane handles 4 channels (1 uint gather/edge)
__global__ __launch_bounds__(256) void agg128f8(
    const unsigned* __restrict__ h4, const int* __restrict__ rs,
    const unsigned* __restrict__ pe, unsigned* __restrict__ outp,
    float* __restrict__ sumP, float* __restrict__ ssP)
{
    __shared__ float SL[1024];
    const int node = blockIdx.x * 8 + (threadIdx.x >> 5);
    const int l = threadIdx.x & 31;
    int j = rs[node];
    const int j1 = rs[node + 1];
    float a0[4], a1[4], a2[4], a3[4];
#pragma unroll
    for (int t = 0; t < 4; ++t) { a0[t] = 0.f; a1[t] = 0.f; a2[t] = 0.f; a3[t] = 0.f; }
    for (; j + 7 < j1; j += 8) {
        unsigned u[8], v[8];
#pragma unroll
        for (int t = 0; t < 8; ++t) u[t] = pe[j + t];
#pragma unroll
        for (int t = 0; t < 8; ++t) v[t] = h4[(long)(u[t] & 0xFFFFu) * 32 + l];
#pragma unroll
        for (int t = 0; t < 8; ++t) {
            const float w = edgew(u[t]);
            const f32x2 lo = __builtin_amdgcn_cvt_pk_f32_fp8((int)v[t], false);
            const f32x2 hi = __builtin_amdgcn_cvt_pk_f32_fp8((int)v[t], true);
            a0[t & 3] = fmaf(w, lo.x, a0[t & 3]);
            a1[t & 3] = fmaf(w, lo.y, a1[t & 3]);
            a2[t & 3] = fmaf(w, hi.x, a2[t & 3]);
            a3[t & 3] = fmaf(w, hi.y, a3[t & 3]);
        }
    }
    for (; j < j1; ++j) {
        const unsigned u = pe[j];
        const unsigned v = h4[(long)(u & 0xFFFFu) * 32 + l];
        const float w = edgew(u);
        const f32x2 lo = __builtin_amdgcn_cvt_pk_f32_fp8((int)v, false);
        const f32x2 hi = __builtin_amdgcn_cvt_pk_f32_fp8((int)v, true);
        a0[0] = fmaf(w, lo.x, a0[0]);
        a1[0] = fmaf(w, lo.y, a1[0]);
        a2[0] = fmaf(w, hi.x, a2[0]);
        a3[0] = fmaf(w, hi.y, a3[0]);
    }
    const float c0 = (a0[0] + a0[1]) + (a0[2] + a0[3]);
    const float c1 = (a1[0] + a1[1]) + (a1[2] + a1[3]);
    const float c2 = (a2[0] + a2[1]) + (a2[2] + a2[3]);
    const float c3 = (a3[0] + a3[1]) + (a3[2] + a3[3]);
    uint2 o;
    o.x = pack2(c0, c1);
    o.y = pack2(c2, c3);
    ((uint2*)outp)[(long)node * 32 + l] = o;
    bnstat_epi(SL, c0, c1, c2, c3, sumP, ssP);
}

// 8 lanes/node, uint2 gathers (bf16 h rows of 32), float4 fp32 output [NN,32]
__global__ __launch_bounds__(256) void agg32b(
    const unsigned* __restrict__ h2, const int* __restrict__ rs,
    const unsigned* __restrict__ pe, float* __restrict__ out)
{
    const int node = blockIdx.x * 32 + (threadIdx.x >> 3);
    if (node >= NN) return;
    const int l = threadIdx.x & 7;
    int j = rs[node];
    const int j1 = rs[node + 1];
    const uint2* hp = (const uint2*)h2;   // rows of 8 uint2
    float xa[4], ya[4], xb[4], yb[4];
#pragma unroll
    for (int t = 0; t < 4; ++t) { xa[t] = 0.f; ya[t] = 0.f; xb[t] = 0.f; yb[t] = 0.f; }
    for (; j + 7 < j1; j += 8) {
        unsigned u[8]; uint2 v[8];
#pragma unroll
        for (int t = 0; t < 8; ++t) u[t] = pe[j + t];
#pragma unroll
        for (int t = 0; t < 8; ++t) v[t] = hp[(long)(u[t] & 0xFFFFu) * 8 + l];
#pragma unroll
        for (int t = 0; t < 8; ++t) {
            const float w = edgew(u[t]);
            xa[t & 3] = fmaf(w, blo(v[t].x), xa[t & 3]);
            ya[t & 3] = fmaf(w, bhi(v[t].x), ya[t & 3]);
            xb[t & 3] = fmaf(w, blo(v[t].y), xb[t & 3]);
            yb[t & 3] = fmaf(w, bhi(v[t].y), yb[t & 3]);
        }
    }
    for (; j < j1; ++j) {
        const unsigned u = pe[j];
        const uint2 v = hp[(long)(u & 0xFFFFu) * 8 + l];
        const float w = edgew(u);
        xa[0] = fmaf(w, blo(v.x), xa[0]); ya[0] = fmaf(w, bhi(v.x), ya[0]);
        xb[0] = fmaf(w, blo(v.y), xb[0]); yb[0] = fmaf(w, bhi(v.y), yb[0]);
    }
    float4 o;
    o.x = (xa[0] + xa[1]) + (xa[2] + xa[3]);
    o.y = (ya[0] + ya[1]) + (ya[2] + ya[3]);
    o.z = (xb[0] + xb[1]) + (xb[2] + xb[3]);
    o.w = (yb[0] + yb[1]) + (yb[2] + yb[3]);
    ((float4*)out)[(long)node * 8 + l] = o;
}

extern "C" void kernel_launch(void* const* d_in, const int* in_sizes, int n_in,
                              void* d_out, int out_size, void* d_ws, size_t ws_size,
                              hipStream_t stream) {
    const float* x   = (const float*)d_in[0];
    const int*   src = (const int*)d_in[1];
    const int*   dst = (const int*)d_in[2];
    const float* ew  = (const float*)d_in[3];
    const float* W0  = (const float*)d_in[4];
    const float* W1  = (const float*)d_in[5];
    const float* W2  = (const float*)d_in[6];
    const float* g0  = (const float*)d_in[7];
    const float* b0  = (const float*)d_in[8];
    const float* g1  = (const float*)d_in[9];
    const float* b1  = (const float*)d_in[10];
    float* out = (float*)d_out;

    // workspace layout (h sized for bf16 [NN,128]; fp8 layers 0/1 alias the front)
    short* h   = (short*)d_ws;                         // fp8 [NN*128] bytes (L0,L1) / bf16 [NN*32] (L2)
    unsigned* x1p = (unsigned*)(h + (size_t)NN * 128); // [NN*64] uints = pre-only bf16x2
    float* st  = (float*)(x1p + (size_t)NN * 64);      // 8448 floats: stat shards + bucket ctrs
    int*  rs   = (int*)(st + 8448);                    // 50004
    unsigned* ebA = (unsigned*)(rs + 50004);           // NBUCK*BCAP staged src|w
    unsigned char* ebB = (unsigned char*)(ebA + NBUCK * BCAP); // NBUCK*BCAP dst low bytes
    unsigned* pe = (unsigned*)(ebB + NBUCK * BCAP);    // NE final packed edges
    short* Bp0 = (short*)(pe + NE);                    // 32768
    short* Bp1 = Bp0 + 32768;                          // 32768
    short* Bp2 = Bp1 + 32768;                          // 8192

    float* sum0P = st;                                 // [NSHARD][128]
    float* ss0P  = st + 2048;
    float* sum1P = st + 4096;
    float* ss1P  = st + 6144;
    int*   bcnt  = (int*)(st + 8192);                  // 256 bucket counters

    // W0 pack + zero stat shards & bucket counters (replaces memset dispatch)
    packb0_k<<<128, 256, 0, stream>>>(W0, Bp0, st);

    // layer-0 GEMM (fp8 h) + W1/W2 packing
    gemm0_k<<<GB0 + 160, 256, 0, stream>>>(x, Bp0, (unsigned char*)h, NN, W1, W2, Bp1, Bp2);

    // edge scatter into bucket staging (separate launch for attribution)
    scatter_k<<<NBLK1, 256, 0, stream>>>(src, dst, ew, bcnt, ebA, ebB);

    // per-bucket local sort -> compact pe + rs
    phase2_k<<<NBUCK, 256, 0, stream>>>(ebA, ebB, bcnt, rs, pe);

    // ---- layer 0 aggregation (fp8 gathers) + fused BN stats ----
    agg128f8<<<6250, 256, 0, stream>>>((const unsigned*)h, rs, pe, x1p, sum0P, ss0P);

    // ---- layer 1 (BN0+ReLU fused into fragment load; fp8 h out) ----
    gemm_bn<8, true><<<782, 256, 0, stream>>>(x1p, Bp1, h, NN, sum0P, ss0P, g0, b0);
    agg128f8<<<6250, 256, 0, stream>>>((const unsigned*)h, rs, pe, x1p, sum1P, ss1P);

    // ---- output layer (bf16 h out) ----
    gemm_bn<2, false><<<782, 256, 0, stream>>>(x1p, Bp2, h, NN, sum1P, ss1P, g1, b1);
    agg32b<<<1563, 256, 0, stream>>>((const unsigned*)h, rs, pe, out);
}

// Round 8
// 240.782 us; speedup vs baseline: 1.0262x; 1.0262x over previous
//
#include <hip/hip_runtime.h>
#include <hip/hip_fp16.h>

#define NN 50000
#define NE 800000
#define GB0 782       // gemm blocks in fused gemm0+scatter
#define NBLK1 391     // scatter blocks, 2048 edges each
#define NBUCK 196     // coarse buckets = dst>>8
#define BCAP 8192     // per-bucket staging capacity (mean 4096, sigma 64 -> 64-sigma margin)
#define NSHARD 16     // BN-stat partial shards

typedef __attribute__((ext_vector_type(8))) short bf16x8;
typedef __attribute__((ext_vector_type(4))) float f32x4;
typedef __attribute__((ext_vector_type(2))) float f32x2;

__device__ inline float blo(unsigned u) { union { unsigned i; float f; } c; c.i = u << 16; return c.f; }
__device__ inline float bhi(unsigned u) { union { unsigned i; float f; } c; c.i = u & 0xFFFF0000u; return c.f; }
__device__ inline unsigned short f2b(float f) {
    union { float f; unsigned u; } c; c.f = f;
    return (unsigned short)((c.u + 0x7FFFu + ((c.u >> 16) & 1u)) >> 16);
}
// 2 fp32 -> packed 2xbf16, RNE. NOTE: v_cvt_pk_bf16_f32 is NOT RNE on gfx950
// (R4 failure: absmax 1.75 -> 4.25). Keep the integer RNE sequence.
__device__ inline unsigned pack2(float x, float y) {
    union { float f; unsigned u; } a, b; a.f = x; b.f = y;
    const unsigned lo = (a.u + 0x7FFFu + ((a.u >> 16) & 1u)) >> 16;
    const unsigned hi = (b.u + 0x7FFFu + ((b.u >> 16) & 1u)) & 0xFFFF0000u;
    return (lo & 0xFFFFu) | hi;
}
__device__ inline float edgew(unsigned u) {
    return __half2float(__ushort_as_half((unsigned short)(u >> 16)));
}
__device__ inline bf16x8 u4_to_b8(unsigned a, unsigned b, unsigned c, unsigned d) {
    union { unsigned u[4]; bf16x8 v; } x;
    x.u[0] = a; x.u[1] = b; x.u[2] = c; x.u[3] = d;
    return x.v;
}
// pack 4 fp32 -> 4 fp8 e4m3 (one uint)
__device__ inline unsigned pk_fp8x4(float a, float b, float c, float d) {
    int t = 0;
    t = __builtin_amdgcn_cvt_pk_fp8_f32(a, b, t, false);
    t = __builtin_amdgcn_cvt_pk_fp8_f32(c, d, t, true);
    return (unsigned)t;
}

// ================= weight packing =================
__device__ __forceinline__ void packb_body(const float* __restrict__ B, short* __restrict__ Bp, int NT, int b)
{
    const int o = b * 256 + threadIdx.x;
    if (o >= 4096 * NT) return;
    const int j = o & 7;
    const int lane = (o >> 3) & 63;
    const int tnt = o >> 9;
    const int nt = tnt % NT, ks = tnt / NT;
    const int k = ks * 32 + (lane >> 4) * 8 + j;
    const int n = nt * 16 + (lane & 15);
    Bp[o] = (short)f2b(B[k * (NT * 16) + n]);
}

// fused: W0 packing + zero-init of BN-stat shards and bucket counters
__global__ __launch_bounds__(256) void packb0_k(const float* __restrict__ W0, short* __restrict__ Bp0,
                                                float* __restrict__ stz)
{
    const int o = blockIdx.x * 256 + threadIdx.x;
    if (o < 8448) stz[o] = 0.f;   // 8192 stat shards + 256 bucket counters
    packb_body(W0, Bp0, 8, blockIdx.x);
}

// ================= MFMA GEMM body =================
// MODE 0: A = fp32 [M,256], split-K staged: two 64x128 half-tiles -> swizzled bf16 LDS (16KB)
// MODE 1: A = x1p pre-only [M,64] uints, per-lane direct loads (frag used twice)
// FP8OUT: C is fp8 e4m3 [M, NT*16] bytes; else bf16 [M, NT*16] shorts
// MODE 1: sum/ss point to NSHARD x 128 partial arrays (reduced in preamble)
template <int NT, int MODE, bool FP8OUT>
__device__ __forceinline__ void gemm_body(
    const void* __restrict__ Av, const short* __restrict__ Bp,
    void* __restrict__ Cv, int M,
    const float* __restrict__ sum, const float* __restrict__ ss,
    const float* __restrict__ gam, const float* __restrict__ bet)
{
    constexpr int TC = (NT > 4) ? 4 : NT;
    constexpr int NCC = TC * 16;
    constexpr int CLB = 4 * 16 * NCC * 4;                       // Cl bytes
    constexpr int SMB = (MODE == 0 && 16384 > CLB) ? 16384 : CLB;
    // smem: MODE 0 = A half-tile (64x64 uints, swizzled) aliased with Cl; else Cl only
    __shared__ __align__(16) unsigned char smem[SMB];
    unsigned* As = (unsigned*)smem;
    __shared__ float scs[128], shs[128];
    const int tid = threadIdx.x;
    const int w = tid >> 6;
    const int lane = tid & 63;
    const int lane15 = lane & 15;
    const int quad = lane >> 4;
    const int row0 = blockIdx.x * 64;
    const int m = row0 + w * 16 + lane15;
    const int mc = (m < M) ? m : 0;

    if (MODE == 1) {
        if (tid < 128) {
            float s = 0.f, q = 0.f;
#pragma unroll
            for (int i = 0; i < NSHARD; ++i) {
                s += sum[i * 128 + tid];
                q += ss[i * 128 + tid];
            }
            const float inv = 1.f / (float)M;
            const float mu = s * inv;
            const float var = q * inv - mu * mu;
            const float sc = gam[tid] * rsqrtf(var + 1e-5f);
            scs[tid] = sc;
            shs[tid] = bet[tid] - mu * sc;
        }
        __syncthreads();
    }

    f32x4 acc[NT];
#pragma unroll
    for (int t = 0; t < NT; ++t) acc[t] = (f32x4){0.f, 0.f, 0.f, 0.f};

    if (MODE == 0) {
        // ---- split-K coalesced stage: 2 halves of 64 rows x 128 fp32 -> bf16x2 LDS ----
        const float* xb = (const float*)Av + (long)row0 * 256;
        const int rlim = M - row0;
        const int ml = w * 16 + lane15;
#pragma unroll
        for (int kh = 0; kh < 2; ++kh) {
            if (kh) __syncthreads();          // all waves done reading previous half
#pragma unroll
            for (int it = 0; it < 4; ++it) {
                const int o = it * 256 + tid;        // 0..1023
                const int r = o >> 4;                // local row 0..63
                const int cc = o & 15;               // 8-float chunk within half-row
                float4 v0 = make_float4(0.f, 0.f, 0.f, 0.f);
                float4 v1 = make_float4(0.f, 0.f, 0.f, 0.f);
                if (r < rlim) {
                    v0 = *(const float4*)&xb[r * 256 + kh * 128 + cc * 8];
                    v1 = *(const float4*)&xb[r * 256 + kh * 128 + cc * 8 + 4];
                }
                *(uint4*)&As[r * 64 + ((cc * 4) ^ ((r & 7) << 2))] =
                    make_uint4(pack2(v0.x, v0.y), pack2(v0.z, v0.w),
                               pack2(v1.x, v1.y), pack2(v1.z, v1.w));
            }
            __syncthreads();
#pragma unroll
            for (int ks4 = 0; ks4 < 4; ++ks4) {
                const int ks = kh * 4 + ks4;
                const bf16x8 af = *(const bf16x8*)&As[ml * 64 + ((ks4 * 16 + quad * 4) ^ ((ml & 7) << 2))];
#pragma unroll
                for (int t = 0; t < NT; ++t) {
                    const bf16x8 bf = *(const bf16x8*)&Bp[(((ks * NT + t) * 64) + lane) * 8];
                    acc[t] = __builtin_amdgcn_mfma_f32_16x16x32_bf16(af, bf, acc[t], 0, 0, 0);
                }
            }
        }
        __syncthreads();   // hand-off: As region reused as Cl below
    } else {
        const unsigned* arow = (const unsigned*)Av + (long)mc * 64;
#pragma unroll
        for (int ks = 0; ks < 4; ++ks) {
            const uint4 pv = *(const uint4*)&arow[ks * 16 + quad * 4];
            const bf16x8 apre = u4_to_b8(pv.x, pv.y, pv.z, pv.w);
            const int c0 = ks * 32 + quad * 8;
            const float4 s0 = *(const float4*)&scs[c0];
            const float4 s1 = *(const float4*)&scs[c0 + 4];
            const float4 h0 = *(const float4*)&shs[c0];
            const float4 h1 = *(const float4*)&shs[c0 + 4];
            const bf16x8 aact = u4_to_b8(
                pack2(fmaxf(fmaf(blo(pv.x), s0.x, h0.x), 0.f), fmaxf(fmaf(bhi(pv.x), s0.y, h0.y), 0.f)),
                pack2(fmaxf(fmaf(blo(pv.y), s0.z, h0.z), 0.f), fmaxf(fmaf(bhi(pv.y), s0.w, h0.w), 0.f)),
                pack2(fmaxf(fmaf(blo(pv.z), s1.x, h1.x), 0.f), fmaxf(fmaf(bhi(pv.z), s1.y, h1.y), 0.f)),
                pack2(fmaxf(fmaf(blo(pv.w), s1.z, h1.z), 0.f), fmaxf(fmaf(bhi(pv.w), s1.w, h1.w), 0.f)));
#pragma unroll
            for (int t = 0; t < NT; ++t) {
                const bf16x8 bf = *(const bf16x8*)&Bp[(((ks * NT + t) * 64) + lane) * 8];
                acc[t] = __builtin_amdgcn_mfma_f32_16x16x32_bf16(aact, bf, acc[t], 0, 0, 0);
            }
#pragma unroll
            for (int t = 0; t < NT; ++t) {
                const bf16x8 bf = *(const bf16x8*)&Bp[((((ks + 4) * NT + t) * 64) + lane) * 8];
                acc[t] = __builtin_amdgcn_mfma_f32_16x16x32_bf16(apre, bf, acc[t], 0, 0, 0);
            }
        }
    }

    // per-wave chunked epilogue: LDS transpose -> pack -> vector stores
    float* cl = (float*)smem + w * 16 * NCC;
#pragma unroll
    for (int t0 = 0; t0 < NT; t0 += TC) {
#pragma unroll
        for (int tt = 0; tt < TC; ++tt)
#pragma unroll
            for (int r = 0; r < 4; ++r)
                cl[(quad * 4 + r) * NCC + tt * 16 + lane15] = acc[t0 + tt][r];
        if (FP8OUT) {
            constexpr int BPL = NCC / 4;     // fp8 bytes per lane
            const int f = lane * BPL;
            const int r = f / NCC;
            const int col = f % NCC;
            const int grow = row0 + w * 16 + r;
            unsigned ou[BPL / 4];
#pragma unroll
            for (int q = 0; q < BPL / 4; ++q) {
                const float4 v = *(const float4*)&cl[f + q * 4];
                ou[q] = pk_fp8x4(v.x, v.y, v.z, v.w);
            }
            if (grow < M) {
                unsigned char* cp = (unsigned char*)Cv + (long)grow * (NT * 16) + t0 * 16 + col;
                if (BPL == 16) *(uint4*)cp = make_uint4(ou[0], ou[1], ou[2], ou[3]);
                else           *(uint2*)cp = make_uint2(ou[0], ou[1]);
            }
        } else {
#pragma unroll
            for (int i = 0; i < (16 * NCC) / 512; ++i) {
                const int f = i * 512 + lane * 8;
                const int r = f / NCC;
                const int col = f % NCC;
                const int grow = row0 + w * 16 + r;
                const float4 lo = *(const float4*)&cl[f];
                const float4 hi = *(const float4*)&cl[f + 4];
                uint4 o;
                o.x = pack2(lo.x, lo.y);
                o.y = pack2(lo.z, lo.w);
                o.z = pack2(hi.x, hi.y);
                o.w = pack2(hi.z, hi.w);
                if (grow < M) *(uint4*)((short*)Cv + (long)grow * (NT * 16) + t0 * 16 + col) = o;
            }
        }
    }
}

// scatter body: per-block LDS hist -> atomic bucket-range reservation -> scatter
// into fixed-capacity bucket regions (no cross-block scan dependency).
__device__ __forceinline__ void scatter_body(
    int k, const int* __restrict__ src, const int* __restrict__ dst, const float* __restrict__ ew,
    int* __restrict__ bcnt, unsigned* __restrict__ ebA, unsigned char* __restrict__ ebB)
{
    __shared__ int cnt[256];
    __shared__ int myoff[256];
    const int t = threadIdx.x;
    cnt[t] = 0;
    __syncthreads();
    const int ebase = k * 2048;
    int d[8];
#pragma unroll
    for (int i = 0; i < 8; ++i) {
        const int e = ebase + i * 256 + t;
        if (e < NE) { d[i] = dst[e]; atomicAdd(&cnt[(unsigned)d[i] >> 8], 1); }
        else d[i] = -1;
    }
    __syncthreads();
    if (t < NBUCK && cnt[t] > 0)
        myoff[t] = t * BCAP + atomicAdd(&bcnt[t], cnt[t]);
    __syncthreads();
#pragma unroll
    for (int i = 0; i < 8; ++i) {
        const int e = ebase + i * 256 + t;
        if (e < NE) {
            const int dd = d[i];
            const int pos = atomicAdd(&myoff[(unsigned)dd >> 8], 1);
            const unsigned wb = (unsigned)__half_as_ushort(__float2half_rn(ew[e]));
            ebA[pos] = ((unsigned)src[e] & 0xFFFFu) | (wb << 16);
            ebB[pos] = (unsigned char)(dd & 255);
        }
    }
}

// fused: layer-0 GEMM (fp8 C, split-K 16KB LDS) + edge scatter + W1/W2 packing
// (fusion buys GEMM/scatter overlap: scatter blocks fill CU slots the
//  latency-bound GEMM under-uses — R6 vs R7 A/B showed the split costs ~7us)
__global__ __launch_bounds__(256) void gemm0_hist1(
    const float* __restrict__ x, const short* __restrict__ Bp, unsigned char* __restrict__ C, int M,
    const int* __restrict__ src, const int* __restrict__ dst, const float* __restrict__ ew,
    int* __restrict__ bcnt, unsigned* __restrict__ ebA, unsigned char* __restrict__ ebB,
    const float* __restrict__ W1, const float* __restrict__ W2,
    short* __restrict__ Bp1, short* __restrict__ Bp2)
{
    if (blockIdx.x < GB0) {
        gemm_body<8, 0, true>(x, Bp, C, M, nullptr, nullptr, nullptr, nullptr);
    } else if (blockIdx.x < GB0 + NBLK1) {
        scatter_body(blockIdx.x - GB0, src, dst, ew, bcnt, ebA, ebB);
    } else if (blockIdx.x < GB0 + NBLK1 + 128) {
        packb_body(W1, Bp1, 8, blockIdx.x - (GB0 + NBLK1));
    } else {
        packb_body(W2, Bp2, 2, blockIdx.x - (GB0 + NBLK1 + 128));
    }
}

// phase2: per bucket (staged at b*BCAP, count bcnt[b]): count -> scan -> rs + compact pe
__global__ __launch_bounds__(256) void phase2_k(
    const unsigned* __restrict__ ebA, const unsigned char* __restrict__ ebB,
    const int* __restrict__ bcnt, int* __restrict__ rs, unsigned* __restrict__ pe)
{
    __shared__ int bscan[256];
    __shared__ int cnt[256];
    __shared__ int cur[256];
    const int b = blockIdx.x;
    const int t = threadIdx.x;
    const int v0 = (t < NBUCK) ? bcnt[t] : 0;
    bscan[t] = v0;
    __syncthreads();
    for (int off = 1; off < 256; off <<= 1) {
        const int x = (t >= off) ? bscan[t - off] : 0;
        __syncthreads();
        bscan[t] += x;
        __syncthreads();
    }
    const int nb = bcnt[b];
    const int e1 = bscan[b];      // compact end
    const int e0 = e1 - nb;       // compact start
    const int i0 = b * BCAP;      // staged start
    cnt[t] = 0;
    __syncthreads();
    for (int i = t; i < nb; i += 256) atomicAdd(&cnt[ebB[i0 + i]], 1);
    __syncthreads();
    const int v = cnt[t];
    __syncthreads();
    for (int off = 1; off < 256; off <<= 1) {
        const int x = (t >= off) ? cnt[t - off] : 0;
        __syncthreads();
        cnt[t] += x;
        __syncthreads();
    }
    const int exc = cnt[t] - v;
    const int node = b * 256 + t;
    if (node < NN) rs[node] = e0 + exc;
    if (b == 0 && t == 0) rs[NN] = NE;
    cur[t] = e0 + exc;
    __syncthreads();
    for (int i = t; i < nb; i += 256) {
        const int e = i0 + i;
        const int pos = atomicAdd(&cur[ebB[e]], 1);
        pe[pos] = ebA[e];
    }
}

template <int NT, bool F8>
__global__ __launch_bounds__(256) void gemm_bn(
    const unsigned* __restrict__ A, const short* __restrict__ Bp, void* __restrict__ C, int M,
    const float* __restrict__ sum, const float* __restrict__ ss,
    const float* __restrict__ gam, const float* __restrict__ bet)
{
    gemm_body<NT, 1, F8>(A, Bp, C, M, sum, ss, gam, bet);
}

// BN-stat epilogue shared by agg kernels: each thread holds 4 channel values (ch 4l..4l+3)
// of one node-slot; LDS-reduce 8 nodes/block, atomicAdd into sharded partials.
__device__ __forceinline__ void bnstat_epi(
    float* __restrict__ SL, float c0, float c1, float c2, float c3,
    float* __restrict__ sumP, float* __restrict__ ssP)
{
    const int slot = threadIdx.x >> 5;
    const int l = threadIdx.x & 31;
    *(float4*)&SL[slot * 128 + l * 4] = make_float4(c0, c1, c2, c3);
    __syncthreads();
    if (threadIdx.x < 128) {
        float s = 0.f, q = 0.f;
#pragma unroll
        for (int i = 0; i < 8; ++i) {
            const float x = SL[i * 128 + threadIdx.x];
            s += x;
            q = fmaf(x, x, q);
        }
        const int sh = (blockIdx.x & (NSHARD - 1)) * 128 + threadIdx.x;
        atomicAdd(&sumP[sh], s);
        atomicAdd(&ssP[sh], q);
    }
}

// ================= aggregation (layers 0 and 1): fp8 h rows (128 B) + fused BN stats =================
// 2 nodes/wave, 32 lanes/node; lane handles 4 channels (1 uint gather/edge)
__global__ __launch_bounds__(256) void agg128f8(
    const unsigned* __restrict__ h4, const int* __restrict__ rs,
    const unsigned* __restrict__ pe, unsigned* __restrict__ outp,
    float* __restrict__ sumP, float* __restrict__ ssP)
{
    __shared__ float SL[1024];
    const int node = blockIdx.x * 8 + (threadIdx.x >> 5);
    const int l = threadIdx.x & 31;
    int j = rs[node];
    const int j1 = rs[node + 1];
    float a0[4], a1[4], a2[4], a3[4];
#pragma unroll
    for (int t = 0; t < 4; ++t) { a0[t] = 0.f; a1[t] = 0.f; a2[t] = 0.f; a3[t] = 0.f; }
    for (; j + 7 < j1; j += 8) {
        unsigned u[8], v[8];
#pragma unroll
        for (int t = 0; t < 8; ++t) u[t] = pe[j + t];
#pragma unroll
        for (int t = 0; t < 8; ++t) v[t] = h4[(long)(u[t] & 0xFFFFu) * 32 + l];
#pragma unroll
        for (int t = 0; t < 8; ++t) {
            const float w = edgew(u[t]);
            const f32x2 lo = __builtin_amdgcn_cvt_pk_f32_fp8((int)v[t], false);
            const f32x2 hi = __builtin_amdgcn_cvt_pk_f32_fp8((int)v[t], true);
            a0[t & 3] = fmaf(w, lo.x, a0[t & 3]);
            a1[t & 3] = fmaf(w, lo.y, a1[t & 3]);
            a2[t & 3] = fmaf(w, hi.x, a2[t & 3]);
            a3[t & 3] = fmaf(w, hi.y, a3[t & 3]);
        }
    }
    for (; j < j1; ++j) {
        const unsigned u = pe[j];
        const unsigned v = h4[(long)(u & 0xFFFFu) * 32 + l];
        const float w = edgew(u);
        const f32x2 lo = __builtin_amdgcn_cvt_pk_f32_fp8((int)v, false);
        const f32x2 hi = __builtin_amdgcn_cvt_pk_f32_fp8((int)v, true);
        a0[0] = fmaf(w, lo.x, a0[0]);
        a1[0] = fmaf(w, lo.y, a1[0]);
        a2[0] = fmaf(w, hi.x, a2[0]);
        a3[0] = fmaf(w, hi.y, a3[0]);
    }
    const float c0 = (a0[0] + a0[1]) + (a0[2] + a0[3]);
    const float c1 = (a1[0] + a1[1]) + (a1[2] + a1[3]);
    const float c2 = (a2[0] + a2[1]) + (a2[2] + a2[3]);
    const float c3 = (a3[0] + a3[1]) + (a3[2] + a3[3]);
    uint2 o;
    o.x = pack2(c0, c1);
    o.y = pack2(c2, c3);
    ((uint2*)outp)[(long)node * 32 + l] = o;
    bnstat_epi(SL, c0, c1, c2, c3, sumP, ssP);
}

// 8 lanes/node, uint2 gathers (bf16 h rows of 32), float4 fp32 output [NN,32]
__global__ __launch_bounds__(256) void agg32b(
    const unsigned* __restrict__ h2, const int* __restrict__ rs,
    const unsigned* __restrict__ pe, float* __restrict__ out)
{
    const int node = blockIdx.x * 32 + (threadIdx.x >> 3);
    if (node >= NN) return;
    const int l = threadIdx.x & 7;
    int j = rs[node];
    const int j1 = rs[node + 1];
    const uint2* hp = (const uint2*)h2;   // rows of 8 uint2
    float xa[4], ya[4], xb[4], yb[4];
#pragma unroll
    for (int t = 0; t < 4; ++t) { xa[t] = 0.f; ya[t] = 0.f; xb[t] = 0.f; yb[t] = 0.f; }
    for (; j + 7 < j1; j += 8) {
        unsigned u[8]; uint2 v[8];
#pragma unroll
        for (int t = 0; t < 8; ++t) u[t] = pe[j + t];
#pragma unroll
        for (int t = 0; t < 8; ++t) v[t] = hp[(long)(u[t] & 0xFFFFu) * 8 + l];
#pragma unroll
        for (int t = 0; t < 8; ++t) {
            const float w = edgew(u[t]);
            xa[t & 3] = fmaf(w, blo(v[t].x), xa[t & 3]);
            ya[t & 3] = fmaf(w, bhi(v[t].x), ya[t & 3]);
            xb[t & 3] = fmaf(w, blo(v[t].y), xb[t & 3]);
            yb[t & 3] = fmaf(w, bhi(v[t].y), yb[t & 3]);
        }
    }
    for (; j < j1; ++j) {
        const unsigned u = pe[j];
        const uint2 v = hp[(long)(u & 0xFFFFu) * 8 + l];
        const float w = edgew(u);
        xa[0] = fmaf(w, blo(v.x), xa[0]); ya[0] = fmaf(w, bhi(v.x), ya[0]);
        xb[0] = fmaf(w, blo(v.y), xb[0]); yb[0] = fmaf(w, bhi(v.y), yb[0]);
    }
    float4 o;
    o.x = (xa[0] + xa[1]) + (xa[2] + xa[3]);
    o.y = (ya[0] + ya[1]) + (ya[2] + ya[3]);
    o.z = (xb[0] + xb[1]) + (xb[2] + xb[3]);
    o.w = (yb[0] + yb[1]) + (yb[2] + yb[3]);
    ((float4*)out)[(long)node * 8 + l] = o;
}

extern "C" void kernel_launch(void* const* d_in, const int* in_sizes, int n_in,
                              void* d_out, int out_size, void* d_ws, size_t ws_size,
                              hipStream_t stream) {
    const float* x   = (const float*)d_in[0];
    const int*   src = (const int*)d_in[1];
    const int*   dst = (const int*)d_in[2];
    const float* ew  = (const float*)d_in[3];
    const float* W0  = (const float*)d_in[4];
    const float* W1  = (const float*)d_in[5];
    const float* W2  = (const float*)d_in[6];
    const float* g0  = (const float*)d_in[7];
    const float* b0  = (const float*)d_in[8];
    const float* g1  = (const float*)d_in[9];
    const float* b1  = (const float*)d_in[10];
    float* out = (float*)d_out;

    // workspace layout (h sized for bf16 [NN,128]; fp8 layers 0/1 alias the front)
    short* h   = (short*)d_ws;                         // fp8 [NN*128] bytes (L0,L1) / bf16 [NN*32] (L2)
    unsigned* x1p = (unsigned*)(h + (size_t)NN * 128); // [NN*64] uints = pre-only bf16x2
    float* st  = (float*)(x1p + (size_t)NN * 64);      // 8448 floats: stat shards + bucket ctrs
    int*  rs   = (int*)(st + 8448);                    // 50004
    unsigned* ebA = (unsigned*)(rs + 50004);           // NBUCK*BCAP staged src|w
    unsigned char* ebB = (unsigned char*)(ebA + NBUCK * BCAP); // NBUCK*BCAP dst low bytes
    unsigned* pe = (unsigned*)(ebB + NBUCK * BCAP);    // NE final packed edges
    short* Bp0 = (short*)(pe + NE);                    // 32768
    short* Bp1 = Bp0 + 32768;                          // 32768
    short* Bp2 = Bp1 + 32768;                          // 8192

    float* sum0P = st;                                 // [NSHARD][128]
    float* ss0P  = st + 2048;
    float* sum1P = st + 4096;
    float* ss1P  = st + 6144;
    int*   bcnt  = (int*)(st + 8192);                  // 256 bucket counters

    // W0 pack + zero stat shards & bucket counters (replaces memset dispatch)
    packb0_k<<<128, 256, 0, stream>>>(W0, Bp0, st);

    // layer-0 GEMM (fp8 h) + edge scatter into bucket staging + W1/W2 packing (one launch)
    gemm0_hist1<<<GB0 + NBLK1 + 160, 256, 0, stream>>>(x, Bp0, (unsigned char*)h, NN,
                                                       src, dst, ew, bcnt, ebA, ebB,
                                                       W1, W2, Bp1, Bp2);

    // per-bucket local sort -> compact pe + rs
    phase2_k<<<NBUCK, 256, 0, stream>>>(ebA, ebB, bcnt, rs, pe);

    // ---- layer 0 aggregation (fp8 gathers) + fused BN stats ----
    agg128f8<<<6250, 256, 0, stream>>>((const unsigned*)h, rs, pe, x1p, sum0P, ss0P);

    // ---- layer 1 (BN0+ReLU fused into fragment load; fp8 h out) ----
    gemm_bn<8, true><<<782, 256, 0, stream>>>(x1p, Bp1, h, NN, sum0P, ss0P, g0, b0);
    agg128f8<<<6250, 256, 0, stream>>>((const unsigned*)h, rs, pe, x1p, sum1P, ss1P);

    // ---- output layer (bf16 h out) ----
    gemm_bn<2, false><<<782, 256, 0, stream>>>(x1p, Bp2, h, NN, sum1P, ss1P, g1, b1);
    agg32b<<<1563, 256, 0, stream>>>((const unsigned*)h, rs, pe, out);
}

// Round 9
// 235.351 us; speedup vs baseline: 1.0499x; 1.0231x over previous
//
#include <hip/hip_runtime.h>
#include <hip/hip_fp16.h>

#define NN 50000
#define NE 800000
#define GB0 782       // gemm blocks
#define NBLK1 391     // scatter blocks, 2048 edges each
#define NBUCK 196     // coarse buckets = dst>>8
#define BCAP 8192     // per-bucket staging capacity (mean 4096, sigma 64 -> 64-sigma margin)
#define NSHARD 16     // BN-stat partial shards

typedef __attribute__((ext_vector_type(8))) short bf16x8;
typedef __attribute__((ext_vector_type(4))) float f32x4;
typedef __attribute__((ext_vector_type(2))) float f32x2;

__device__ inline float blo(unsigned u) { union { unsigned i; float f; } c; c.i = u << 16; return c.f; }
__device__ inline float bhi(unsigned u) { union { unsigned i; float f; } c; c.i = u & 0xFFFF0000u; return c.f; }
__device__ inline unsigned short f2b(float f) {
    union { float f; unsigned u; } c; c.f = f;
    return (unsigned short)((c.u + 0x7FFFu + ((c.u >> 16) & 1u)) >> 16);
}
// 2 fp32 -> packed 2xbf16, RNE. NOTE: v_cvt_pk_bf16_f32 is NOT RNE on gfx950
// (R4 failure: absmax 1.75 -> 4.25). Keep the integer RNE sequence.
__device__ inline unsigned pack2(float x, float y) {
    union { float f; unsigned u; } a, b; a.f = x; b.f = y;
    const unsigned lo = (a.u + 0x7FFFu + ((a.u >> 16) & 1u)) >> 16;
    const unsigned hi = (b.u + 0x7FFFu + ((b.u >> 16) & 1u)) & 0xFFFF0000u;
    return (lo & 0xFFFFu) | hi;
}
__device__ inline float edgew(unsigned u) {
    return __half2float(__ushort_as_half((unsigned short)(u >> 16)));
}
__device__ inline bf16x8 u4_to_b8(unsigned a, unsigned b, unsigned c, unsigned d) {
    union { unsigned u[4]; bf16x8 v; } x;
    x.u[0] = a; x.u[1] = b; x.u[2] = c; x.u[3] = d;
    return x.v;
}
// pack 4 fp32 -> 4 fp8 e4m3 (one uint)
__device__ inline unsigned pk_fp8x4(float a, float b, float c, float d) {
    int t = 0;
    t = __builtin_amdgcn_cvt_pk_fp8_f32(a, b, t, false);
    t = __builtin_amdgcn_cvt_pk_fp8_f32(c, d, t, true);
    return (unsigned)t;
}

// ================= weight packing =================
__device__ __forceinline__ void packb_body(const float* __restrict__ B, short* __restrict__ Bp, int NT, int b)
{
    const int o = b * 256 + threadIdx.x;
    if (o >= 4096 * NT) return;
    const int j = o & 7;
    const int lane = (o >> 3) & 63;
    const int tnt = o >> 9;
    const int nt = tnt % NT, ks = tnt / NT;
    const int k = ks * 32 + (lane >> 4) * 8 + j;
    const int n = nt * 16 + (lane & 15);
    Bp[o] = (short)f2b(B[k * (NT * 16) + n]);
}

// scatter body: per-block LDS hist -> atomic bucket-range reservation -> scatter
// into fixed-capacity bucket regions (no cross-block scan dependency).
__device__ __forceinline__ void scatter_body(
    int k, const int* __restrict__ src, const int* __restrict__ dst, const float* __restrict__ ew,
    int* __restrict__ bcnt, unsigned* __restrict__ ebA, unsigned char* __restrict__ ebB)
{
    __shared__ int cnt[256];
    __shared__ int myoff[256];
    const int t = threadIdx.x;
    cnt[t] = 0;
    __syncthreads();
    const int ebase = k * 2048;
    int d[8];
#pragma unroll
    for (int i = 0; i < 8; ++i) {
        const int e = ebase + i * 256 + t;
        if (e < NE) { d[i] = dst[e]; atomicAdd(&cnt[(unsigned)d[i] >> 8], 1); }
        else d[i] = -1;
    }
    __syncthreads();
    if (t < NBUCK && cnt[t] > 0)
        myoff[t] = t * BCAP + atomicAdd(&bcnt[t], cnt[t]);
    __syncthreads();
#pragma unroll
    for (int i = 0; i < 8; ++i) {
        const int e = ebase + i * 256 + t;
        if (e < NE) {
            const int dd = d[i];
            const int pos = atomicAdd(&myoff[(unsigned)dd >> 8], 1);
            const unsigned wb = (unsigned)__half_as_ushort(__float2half_rn(ew[e]));
            ebA[pos] = ((unsigned)src[e] & 0xFFFFu) | (wb << 16);
            ebB[pos] = (unsigned char)(dd & 255);
        }
    }
}

// L1: edge scatter (first, bulk) + W0 packing (zero-init now via hipMemsetAsync)
__global__ __launch_bounds__(256) void scat_packb0_k(
    const int* __restrict__ src, const int* __restrict__ dst, const float* __restrict__ ew,
    int* __restrict__ bcnt, unsigned* __restrict__ ebA, unsigned char* __restrict__ ebB,
    const float* __restrict__ W0, short* __restrict__ Bp0)
{
    if (blockIdx.x < NBLK1) {
        scatter_body(blockIdx.x, src, dst, ew, bcnt, ebA, ebB);
    } else {
        packb_body(W0, Bp0, 8, blockIdx.x - NBLK1);
    }
}

// ================= MFMA GEMM body =================
// MODE 0: A = fp32 [M,256], split-K staged: two 64x128 half-tiles -> swizzled bf16 LDS (16KB)
// MODE 1: A = x1p pre-only [M,64] uints, per-lane direct loads (frag used twice)
// FP8OUT: C is fp8 e4m3 [M, NT*16] bytes; else bf16 [M, NT*16] shorts
// MODE 1: sum/ss point to NSHARD x 128 partial arrays (reduced in preamble)
template <int NT, int MODE, bool FP8OUT>
__device__ __forceinline__ void gemm_body(
    const void* __restrict__ Av, const short* __restrict__ Bp,
    void* __restrict__ Cv, int M, int gb,
    const float* __restrict__ sum, const float* __restrict__ ss,
    const float* __restrict__ gam, const float* __restrict__ bet)
{
    constexpr int TC = (NT > 4) ? 4 : NT;
    constexpr int NCC = TC * 16;
    constexpr int CLB = 4 * 16 * NCC * 4;                       // Cl bytes
    constexpr int SMB = (MODE == 0 && 16384 > CLB) ? 16384 : CLB;
    // smem: MODE 0 = A half-tile (64x64 uints, swizzled) aliased with Cl; else Cl only
    __shared__ __align__(16) unsigned char smem[SMB];
    unsigned* As = (unsigned*)smem;
    __shared__ float scs[128], shs[128];
    const int tid = threadIdx.x;
    const int w = tid >> 6;
    const int lane = tid & 63;
    const int lane15 = lane & 15;
    const int quad = lane >> 4;
    const int row0 = gb * 64;
    const int m = row0 + w * 16 + lane15;
    const int mc = (m < M) ? m : 0;

    if (MODE == 1) {
        if (tid < 128) {
            float s = 0.f, q = 0.f;
#pragma unroll
            for (int i = 0; i < NSHARD; ++i) {
                s += sum[i * 128 + tid];
                q += ss[i * 128 + tid];
            }
            const float inv = 1.f / (float)M;
            const float mu = s * inv;
            const float var = q * inv - mu * mu;
            const float sc = gam[tid] * rsqrtf(var + 1e-5f);
            scs[tid] = sc;
            shs[tid] = bet[tid] - mu * sc;
        }
        __syncthreads();
    }

    f32x4 acc[NT];
#pragma unroll
    for (int t = 0; t < NT; ++t) acc[t] = (f32x4){0.f, 0.f, 0.f, 0.f};

    if (MODE == 0) {
        // ---- split-K coalesced stage: 2 halves of 64 rows x 128 fp32 -> bf16x2 LDS ----
        const float* xb = (const float*)Av + (long)row0 * 256;
        const int rlim = M - row0;
        const int ml = w * 16 + lane15;
#pragma unroll
        for (int kh = 0; kh < 2; ++kh) {
            if (kh) __syncthreads();          // all waves done reading previous half
#pragma unroll
            for (int it = 0; it < 4; ++it) {
                const int o = it * 256 + tid;        // 0..1023
                const int r = o >> 4;                // local row 0..63
                const int cc = o & 15;               // 8-float chunk within half-row
                float4 v0 = make_float4(0.f, 0.f, 0.f, 0.f);
                float4 v1 = make_float4(0.f, 0.f, 0.f, 0.f);
                if (r < rlim) {
                    v0 = *(const float4*)&xb[r * 256 + kh * 128 + cc * 8];
                    v1 = *(const float4*)&xb[r * 256 + kh * 128 + cc * 8 + 4];
                }
                *(uint4*)&As[r * 64 + ((cc * 4) ^ ((r & 7) << 2))] =
                    make_uint4(pack2(v0.x, v0.y), pack2(v0.z, v0.w),
                               pack2(v1.x, v1.y), pack2(v1.z, v1.w));
            }
            __syncthreads();
#pragma unroll
            for (int ks4 = 0; ks4 < 4; ++ks4) {
                const int ks = kh * 4 + ks4;
                const bf16x8 af = *(const bf16x8*)&As[ml * 64 + ((ks4 * 16 + quad * 4) ^ ((ml & 7) << 2))];
#pragma unroll
                for (int t = 0; t < NT; ++t) {
                    const bf16x8 bf = *(const bf16x8*)&Bp[(((ks * NT + t) * 64) + lane) * 8];
                    acc[t] = __builtin_amdgcn_mfma_f32_16x16x32_bf16(af, bf, acc[t], 0, 0, 0);
                }
            }
        }
        __syncthreads();   // hand-off: As region reused as Cl below
    } else {
        const unsigned* arow = (const unsigned*)Av + (long)mc * 64;
#pragma unroll
        for (int ks = 0; ks < 4; ++ks) {
            const uint4 pv = *(const uint4*)&arow[ks * 16 + quad * 4];
            const bf16x8 apre = u4_to_b8(pv.x, pv.y, pv.z, pv.w);
            const int c0 = ks * 32 + quad * 8;
            const float4 s0 = *(const float4*)&scs[c0];
            const float4 s1 = *(const float4*)&scs[c0 + 4];
            const float4 h0 = *(const float4*)&shs[c0];
            const float4 h1 = *(const float4*)&shs[c0 + 4];
            const bf16x8 aact = u4_to_b8(
                pack2(fmaxf(fmaf(blo(pv.x), s0.x, h0.x), 0.f), fmaxf(fmaf(bhi(pv.x), s0.y, h0.y), 0.f)),
                pack2(fmaxf(fmaf(blo(pv.y), s0.z, h0.z), 0.f), fmaxf(fmaf(bhi(pv.y), s0.w, h0.w), 0.f)),
                pack2(fmaxf(fmaf(blo(pv.z), s1.x, h1.x), 0.f), fmaxf(fmaf(bhi(pv.z), s1.y, h1.y), 0.f)),
                pack2(fmaxf(fmaf(blo(pv.w), s1.z, h1.z), 0.f), fmaxf(fmaf(bhi(pv.w), s1.w, h1.w), 0.f)));
#pragma unroll
            for (int t = 0; t < NT; ++t) {
                const bf16x8 bf = *(const bf16x8*)&Bp[(((ks * NT + t) * 64) + lane) * 8];
                acc[t] = __builtin_amdgcn_mfma_f32_16x16x32_bf16(aact, bf, acc[t], 0, 0, 0);
            }
#pragma unroll
            for (int t = 0; t < NT; ++t) {
                const bf16x8 bf = *(const bf16x8*)&Bp[((((ks + 4) * NT + t) * 64) + lane) * 8];
                acc[t] = __builtin_amdgcn_mfma_f32_16x16x32_bf16(apre, bf, acc[t], 0, 0, 0);
            }
        }
    }

    // per-wave chunked epilogue: LDS transpose -> pack -> vector stores
    float* cl = (float*)smem + w * 16 * NCC;
#pragma unroll
    for (int t0 = 0; t0 < NT; t0 += TC) {
#pragma unroll
        for (int tt = 0; tt < TC; ++tt)
#pragma unroll
            for (int r = 0; r < 4; ++r)
                cl[(quad * 4 + r) * NCC + tt * 16 + lane15] = acc[t0 + tt][r];
        if (FP8OUT) {
            constexpr int BPL = NCC / 4;     // fp8 bytes per lane
            const int f = lane * BPL;
            const int r = f / NCC;
            const int col = f % NCC;
            const int grow = row0 + w * 16 + r;
            unsigned ou[BPL / 4];
#pragma unroll
            for (int q = 0; q < BPL / 4; ++q) {
                const float4 v = *(const float4*)&cl[f + q * 4];
                ou[q] = pk_fp8x4(v.x, v.y, v.z, v.w);
            }
            if (grow < M) {
                unsigned char* cp = (unsigned char*)Cv + (long)grow * (NT * 16) + t0 * 16 + col;
                if (BPL == 16) *(uint4*)cp = make_uint4(ou[0], ou[1], ou[2], ou[3]);
                else           *(uint2*)cp = make_uint2(ou[0], ou[1]);
            }
        } else {
#pragma unroll
            for (int i = 0; i < (16 * NCC) / 512; ++i) {
                const int f = i * 512 + lane * 8;
                const int r = f / NCC;
                const int col = f % NCC;
                const int grow = row0 + w * 16 + r;
                const float4 lo = *(const float4*)&cl[f];
                const float4 hi = *(const float4*)&cl[f + 4];
                uint4 o;
                o.x = pack2(lo.x, lo.y);
                o.y = pack2(lo.z, lo.w);
                o.z = pack2(hi.x, hi.y);
                o.w = pack2(hi.z, hi.w);
                if (grow < M) *(uint4*)((short*)Cv + (long)grow * (NT * 16) + t0 * 16 + col) = o;
            }
        }
    }
}

// phase2 body: per bucket (staged at b*BCAP, count bcnt[b]): count -> scan -> rs + compact pe
__device__ __forceinline__ void phase2_body(
    int b, const unsigned* __restrict__ ebA, const unsigned char* __restrict__ ebB,
    const int* __restrict__ bcnt, int* __restrict__ rs, unsigned* __restrict__ pe)
{
    __shared__ int bscan[256];
    __shared__ int cnt[256];
    __shared__ int cur[256];
    const int t = threadIdx.x;
    const int v0 = (t < NBUCK) ? bcnt[t] : 0;
    bscan[t] = v0;
    __syncthreads();
    for (int off = 1; off < 256; off <<= 1) {
        const int x = (t >= off) ? bscan[t - off] : 0;
        __syncthreads();
        bscan[t] += x;
        __syncthreads();
    }
    const int nb = bcnt[b];
    const int e1 = bscan[b];      // compact end
    const int e0 = e1 - nb;       // compact start
    const int i0 = b * BCAP;      // staged start
    cnt[t] = 0;
    __syncthreads();
    for (int i = t; i < nb; i += 256) atomicAdd(&cnt[ebB[i0 + i]], 1);
    __syncthreads();
    const int v = cnt[t];
    __syncthreads();
    for (int off = 1; off < 256; off <<= 1) {
        const int x = (t >= off) ? cnt[t - off] : 0;
        __syncthreads();
        cnt[t] += x;
        __syncthreads();
    }
    const int exc = cnt[t] - v;
    const int node = b * 256 + t;
    if (node < NN) rs[node] = e0 + exc;
    if (b == 0 && t == 0) rs[NN] = NE;
    cur[t] = e0 + exc;
    __syncthreads();
    for (int i = t; i < nb; i += 256) {
        const int e = i0 + i;
        const int pos = atomicAdd(&cur[ebB[e]], 1);
        pe[pos] = ebA[e];
    }
}

// L2: phase2 (independent of GEMM, hidden under it) + layer-0 GEMM + W1/W2 packing
__global__ __launch_bounds__(256) void gemm0_p2(
    const float* __restrict__ x, const short* __restrict__ Bp, unsigned char* __restrict__ C, int M,
    const unsigned* __restrict__ ebA, const unsigned char* __restrict__ ebB,
    const int* __restrict__ bcnt, int* __restrict__ rs, unsigned* __restrict__ pe,
    const float* __restrict__ W1, const float* __restrict__ W2,
    short* __restrict__ Bp1, short* __restrict__ Bp2)
{
    if (blockIdx.x < NBUCK) {
        phase2_body(blockIdx.x, ebA, ebB, bcnt, rs, pe);
    } else if (blockIdx.x < NBUCK + GB0) {
        gemm_body<8, 0, true>(x, Bp, C, M, blockIdx.x - NBUCK, nullptr, nullptr, nullptr, nullptr);
    } else if (blockIdx.x < NBUCK + GB0 + 128) {
        packb_body(W1, Bp1, 8, blockIdx.x - (NBUCK + GB0));
    } else {
        packb_body(W2, Bp2, 2, blockIdx.x - (NBUCK + GB0 + 128));
    }
}

template <int NT, bool F8>
__global__ __launch_bounds__(256) void gemm_bn(
    const unsigned* __restrict__ A, const short* __restrict__ Bp, void* __restrict__ C, int M,
    const float* __restrict__ sum, const float* __restrict__ ss,
    const float* __restrict__ gam, const float* __restrict__ bet)
{
    gemm_body<NT, 1, F8>(A, Bp, C, M, blockIdx.x, sum, ss, gam, bet);
}

// BN-stat epilogue shared by agg kernels: each thread holds 4 channel values (ch 4l..4l+3)
// of one node-slot; LDS-reduce 8 nodes/block, atomicAdd into sharded partials.
__device__ __forceinline__ void bnstat_epi(
    float* __restrict__ SL, float c0, float c1, float c2, float c3,
    float* __restrict__ sumP, float* __restrict__ ssP)
{
    const int slot = threadIdx.x >> 5;
    const int l = threadIdx.x & 31;
    *(float4*)&SL[slot * 128 + l * 4] = make_float4(c0, c1, c2, c3);
    __syncthreads();
    if (threadIdx.x < 128) {
        float s = 0.f, q = 0.f;
#pragma unroll
        for (int i = 0; i < 8; ++i) {
            const float x = SL[i * 128 + threadIdx.x];
            s += x;
            q = fmaf(x, x, q);
        }
        const int sh = (blockIdx.x & (NSHARD - 1)) * 128 + threadIdx.x;
        atomicAdd(&sumP[sh], s);
        atomicAdd(&ssP[sh], q);
    }
}

// ================= aggregation (layers 0 and 1): fp8 h rows (128 B) + fused BN stats =================
// 2 nodes/wave, 32 lanes/node; lane handles 4 channels (1 uint gather/edge)
__global__ __launch_bounds__(256) void agg128f8(
    const unsigned* __restrict__ h4, const int* __restrict__ rs,
    const unsigned* __restrict__ pe, unsigned* __restrict__ outp,
    float* __restrict__ sumP, float* __restrict__ ssP)
{
    __shared__ float SL[1024];
    const int node = blockIdx.x * 8 + (threadIdx.x >> 5);
    const int l = threadIdx.x & 31;
    int j = rs[node];
    const int j1 = rs[node + 1];
    float a0[4], a1[4], a2[4], a3[4];
#pragma unroll
    for (int t = 0; t < 4; ++t) { a0[t] = 0.f; a1[t] = 0.f; a2[t] = 0.f; a3[t] = 0.f; }
    for (; j + 7 < j1; j += 8) {
        unsigned u[8], v[8];
#pragma unroll
        for (int t = 0; t < 8; ++t) u[t] = pe[j + t];
#pragma unroll
        for (int t = 0; t < 8; ++t) v[t] = h4[(long)(u[t] & 0xFFFFu) * 32 + l];
#pragma unroll
        for (int t = 0; t < 8; ++t) {
            const float w = edgew(u[t]);
            const f32x2 lo = __builtin_amdgcn_cvt_pk_f32_fp8((int)v[t], false);
            const f32x2 hi = __builtin_amdgcn_cvt_pk_f32_fp8((int)v[t], true);
            a0[t & 3] = fmaf(w, lo.x, a0[t & 3]);
            a1[t & 3] = fmaf(w, lo.y, a1[t & 3]);
            a2[t & 3] = fmaf(w, hi.x, a2[t & 3]);
            a3[t & 3] = fmaf(w, hi.y, a3[t & 3]);
        }
    }
    for (; j < j1; ++j) {
        const unsigned u = pe[j];
        const unsigned v = h4[(long)(u & 0xFFFFu) * 32 + l];
        const float w = edgew(u);
        const f32x2 lo = __builtin_amdgcn_cvt_pk_f32_fp8((int)v, false);
        const f32x2 hi = __builtin_amdgcn_cvt_pk_f32_fp8((int)v, true);
        a0[0] = fmaf(w, lo.x, a0[0]);
        a1[0] = fmaf(w, lo.y, a1[0]);
        a2[0] = fmaf(w, hi.x, a2[0]);
        a3[0] = fmaf(w, hi.y, a3[0]);
    }
    const float c0 = (a0[0] + a0[1]) + (a0[2] + a0[3]);
    const float c1 = (a1[0] + a1[1]) + (a1[2] + a1[3]);
    const float c2 = (a2[0] + a2[1]) + (a2[2] + a2[3]);
    const float c3 = (a3[0] + a3[1]) + (a3[2] + a3[3]);
    uint2 o;
    o.x = pack2(c0, c1);
    o.y = pack2(c2, c3);
    ((uint2*)outp)[(long)node * 32 + l] = o;
    bnstat_epi(SL, c0, c1, c2, c3, sumP, ssP);
}

// 8 lanes/node, uint2 gathers (bf16 h rows of 32), float4 fp32 output [NN,32]
__global__ __launch_bounds__(256) void agg32b(
    const unsigned* __restrict__ h2, const int* __restrict__ rs,
    const unsigned* __restrict__ pe, float* __restrict__ out)
{
    const int node = blockIdx.x * 32 + (threadIdx.x >> 3);
    if (node >= NN) return;
    const int l = threadIdx.x & 7;
    int j = rs[node];
    const int j1 = rs[node + 1];
    const uint2* hp = (const uint2*)h2;   // rows of 8 uint2
    float xa[4], ya[4], xb[4], yb[4];
#pragma unroll
    for (int t = 0; t < 4; ++t) { xa[t] = 0.f; ya[t] = 0.f; xb[t] = 0.f; yb[t] = 0.f; }
    for (; j + 7 < j1; j += 8) {
        unsigned u[8]; uint2 v[8];
#pragma unroll
        for (int t = 0; t < 8; ++t) u[t] = pe[j + t];
#pragma unroll
        for (int t = 0; t < 8; ++t) v[t] = hp[(long)(u[t] & 0xFFFFu) * 8 + l];
#pragma unroll
        for (int t = 0; t < 8; ++t) {
            const float w = edgew(u[t]);
            xa[t & 3] = fmaf(w, blo(v[t].x), xa[t & 3]);
            ya[t & 3] = fmaf(w, bhi(v[t].x), ya[t & 3]);
            xb[t & 3] = fmaf(w, blo(v[t].y), xb[t & 3]);
            yb[t & 3] = fmaf(w, bhi(v[t].y), yb[t & 3]);
        }
    }
    for (; j < j1; ++j) {
        const unsigned u = pe[j];
        const uint2 v = hp[(long)(u & 0xFFFFu) * 8 + l];
        const float w = edgew(u);
        xa[0] = fmaf(w, blo(v.x), xa[0]); ya[0] = fmaf(w, bhi(v.x), ya[0]);
        xb[0] = fmaf(w, blo(v.y), xb[0]); yb[0] = fmaf(w, bhi(v.y), yb[0]);
    }
    float4 o;
    o.x = (xa[0] + xa[1]) + (xa[2] + xa[3]);
    o.y = (ya[0] + ya[1]) + (ya[2] + ya[3]);
    o.z = (xb[0] + xb[1]) + (xb[2] + xb[3]);
    o.w = (yb[0] + yb[1]) + (yb[2] + yb[3]);
    ((float4*)out)[(long)node * 8 + l] = o;
}

extern "C" void kernel_launch(void* const* d_in, const int* in_sizes, int n_in,
                              void* d_out, int out_size, void* d_ws, size_t ws_size,
                              hipStream_t stream) {
    const float* x   = (const float*)d_in[0];
    const int*   src = (const int*)d_in[1];
    const int*   dst = (const int*)d_in[2];
    const float* ew  = (const float*)d_in[3];
    const float* W0  = (const float*)d_in[4];
    const float* W1  = (const float*)d_in[5];
    const float* W2  = (const float*)d_in[6];
    const float* g0  = (const float*)d_in[7];
    const float* b0  = (const float*)d_in[8];
    const float* g1  = (const float*)d_in[9];
    const float* b1  = (const float*)d_in[10];
    float* out = (float*)d_out;

    // workspace layout (h sized for bf16 [NN,128]; fp8 layers 0/1 alias the front)
    short* h   = (short*)d_ws;                         // fp8 [NN*128] bytes (L0,L1) / bf16 [NN*32] (L2)
    unsigned* x1p = (unsigned*)(h + (size_t)NN * 128); // [NN*64] uints = pre-only bf16x2
    float* st  = (float*)(x1p + (size_t)NN * 64);      // 8448 floats: stat shards + bucket ctrs
    int*  rs   = (int*)(st + 8448);                    // 50004
    unsigned* ebA = (unsigned*)(rs + 50004);           // NBUCK*BCAP staged src|w
    unsigned char* ebB = (unsigned char*)(ebA + NBUCK * BCAP); // NBUCK*BCAP dst low bytes
    unsigned* pe = (unsigned*)(ebB + NBUCK * BCAP);    // NE final packed edges
    short* Bp0 = (short*)(pe + NE);                    // 32768
    short* Bp1 = Bp0 + 32768;                          // 32768
    short* Bp2 = Bp1 + 32768;                          // 8192

    float* sum0P = st;                                 // [NSHARD][128]
    float* ss0P  = st + 2048;
    float* sum1P = st + 4096;
    float* ss1P  = st + 6144;
    int*   bcnt  = (int*)(st + 8192);                  // 256 bucket counters

    // zero stat shards & bucket counters (must complete before scatter's atomics)
    hipMemsetAsync(st, 0, 8448 * 4, stream);

    // L1: edge scatter into bucket staging + W0 pack
    scat_packb0_k<<<NBLK1 + 128, 256, 0, stream>>>(src, dst, ew, bcnt, ebA, ebB, W0, Bp0);

    // L2: phase2 (hidden under GEMM) + layer-0 GEMM (fp8 h) + W1/W2 packing
    gemm0_p2<<<NBUCK + GB0 + 160, 256, 0, stream>>>(x, Bp0, (unsigned char*)h, NN,
                                                    ebA, ebB, bcnt, rs, pe,
                                                    W1, W2, Bp1, Bp2);

    // ---- layer 0 aggregation (fp8 gathers) + fused BN stats ----
    agg128f8<<<6250, 256, 0, stream>>>((const unsigned*)h, rs, pe, x1p, sum0P, ss0P);

    // ---- layer 1 (BN0+ReLU fused into fragment load; fp8 h out) ----
    gemm_bn<8, true><<<782, 256, 0, stream>>>(x1p, Bp1, h, NN, sum0P, ss0P, g0, b0);
    agg128f8<<<6250, 256, 0, stream>>>((const unsigned*)h, rs, pe, x1p, sum1P, ss1P);

    // ---- output layer (bf16 h out) ----
    gemm_bn<2, false><<<782, 256, 0, stream>>>(x1p, Bp2, h, NN, sum1P, ss1P, g1, b1);
    agg32b<<<1563, 256, 0, stream>>>((const unsigned*)h, rs, pe, out);
}

// Round 10
// 226.500 us; speedup vs baseline: 1.0910x; 1.0391x over previous
//
#include <hip/hip_runtime.h>
#include <hip/hip_fp16.h>

#define NN 50000
#define NE 800000
#define GB0 782       // gemm blocks
#define NBLK1 391     // scatter blocks, 2048 edges each
#define NBUCK 196     // coarse buckets = dst>>8
#define BCAP 8192     // per-bucket staging capacity (mean 4096, sigma 64 -> 64-sigma margin)
#define NSHARD 16     // BN-stat partial shards

typedef __attribute__((ext_vector_type(8))) short bf16x8;
typedef __attribute__((ext_vector_type(4))) float f32x4;
typedef __attribute__((ext_vector_type(2))) float f32x2;

__device__ inline float blo(unsigned u) { union { unsigned i; float f; } c; c.i = u << 16; return c.f; }
__device__ inline float bhi(unsigned u) { union { unsigned i; float f; } c; c.i = u & 0xFFFF0000u; return c.f; }
__device__ inline unsigned short f2b(float f) {
    union { float f; unsigned u; } c; c.f = f;
    return (unsigned short)((c.u + 0x7FFFu + ((c.u >> 16) & 1u)) >> 16);
}
// 2 fp32 -> packed 2xbf16, RNE. NOTE: v_cvt_pk_bf16_f32 is NOT RNE on gfx950
// (R4 failure: absmax 1.75 -> 4.25). Keep the integer RNE sequence.
__device__ inline unsigned pack2(float x, float y) {
    union { float f; unsigned u; } a, b; a.f = x; b.f = y;
    const unsigned lo = (a.u + 0x7FFFu + ((a.u >> 16) & 1u)) >> 16;
    const unsigned hi = (b.u + 0x7FFFu + ((b.u >> 16) & 1u)) & 0xFFFF0000u;
    return (lo & 0xFFFFu) | hi;
}
__device__ inline float edgew(unsigned u) {
    return __half2float(__ushort_as_half((unsigned short)(u >> 16)));
}
__device__ inline bf16x8 u4_to_b8(unsigned a, unsigned b, unsigned c, unsigned d) {
    union { unsigned u[4]; bf16x8 v; } x;
    x.u[0] = a; x.u[1] = b; x.u[2] = c; x.u[3] = d;
    return x.v;
}
// pack 4 fp32 -> 4 fp8 e4m3 (one uint)
__device__ inline unsigned pk_fp8x4(float a, float b, float c, float d) {
    int t = 0;
    t = __builtin_amdgcn_cvt_pk_fp8_f32(a, b, t, false);
    t = __builtin_amdgcn_cvt_pk_fp8_f32(c, d, t, true);
    return (unsigned)t;
}

// ================= weight packing =================
__device__ __forceinline__ void packb_body(const float* __restrict__ B, short* __restrict__ Bp, int NT, int b)
{
    const int o = b * 256 + threadIdx.x;
    if (o >= 4096 * NT) return;
    const int j = o & 7;
    const int lane = (o >> 3) & 63;
    const int tnt = o >> 9;
    const int nt = tnt % NT, ks = tnt / NT;
    const int k = ks * 32 + (lane >> 4) * 8 + j;
    const int n = nt * 16 + (lane & 15);
    Bp[o] = (short)f2b(B[k * (NT * 16) + n]);
}

// scatter body: per-block LDS hist -> atomic bucket-range reservation -> scatter
// into fixed-capacity bucket regions (no cross-block scan dependency).
__device__ __forceinline__ void scatter_body(
    int k, const int* __restrict__ src, const int* __restrict__ dst, const float* __restrict__ ew,
    int* __restrict__ bcnt, unsigned* __restrict__ ebA, unsigned char* __restrict__ ebB)
{
    __shared__ int cnt[256];
    __shared__ int myoff[256];
    const int t = threadIdx.x;
    cnt[t] = 0;
    __syncthreads();
    const int ebase = k * 2048;
    int d[8];
#pragma unroll
    for (int i = 0; i < 8; ++i) {
        const int e = ebase + i * 256 + t;
        if (e < NE) { d[i] = dst[e]; atomicAdd(&cnt[(unsigned)d[i] >> 8], 1); }
        else d[i] = -1;
    }
    __syncthreads();
    if (t < NBUCK && cnt[t] > 0)
        myoff[t] = t * BCAP + atomicAdd(&bcnt[t], cnt[t]);
    __syncthreads();
#pragma unroll
    for (int i = 0; i < 8; ++i) {
        const int e = ebase + i * 256 + t;
        if (e < NE) {
            const int dd = d[i];
            const int pos = atomicAdd(&myoff[(unsigned)dd >> 8], 1);
            const unsigned wb = (unsigned)__half_as_ushort(__float2half_rn(ew[e]));
            ebA[pos] = ((unsigned)src[e] & 0xFFFFu) | (wb << 16);
            ebB[pos] = (unsigned char)(dd & 255);
        }
    }
}

// L1: edge scatter (first, bulk) + W0 packing (zero-init via hipMemsetAsync)
__global__ __launch_bounds__(256) void scat_packb0_k(
    const int* __restrict__ src, const int* __restrict__ dst, const float* __restrict__ ew,
    int* __restrict__ bcnt, unsigned* __restrict__ ebA, unsigned char* __restrict__ ebB,
    const float* __restrict__ W0, short* __restrict__ Bp0)
{
    if (blockIdx.x < NBLK1) {
        scatter_body(blockIdx.x, src, dst, ew, bcnt, ebA, ebB);
    } else {
        packb_body(W0, Bp0, 8, blockIdx.x - NBLK1);
    }
}

// ================= MFMA GEMM body =================
// MODE 0: A = fp32 [M,256], split-K staged: two 64x128 half-tiles -> swizzled bf16 LDS (16KB)
// MODE 1: A = x1p pre-only [M,64] uints, per-lane direct loads (frag used twice)
// FP8OUT: C is fp8 e4m3 [M, NT*16] bytes; else bf16 [M, NT*16] shorts
// MODE 1: sum/ss point to NSHARD x 128 partial arrays (reduced in preamble)
template <int NT, int MODE, bool FP8OUT>
__device__ __forceinline__ void gemm_body(
    const void* __restrict__ Av, const short* __restrict__ Bp,
    void* __restrict__ Cv, int M, int gb,
    const float* __restrict__ sum, const float* __restrict__ ss,
    const float* __restrict__ gam, const float* __restrict__ bet)
{
    constexpr int TC = (NT > 4) ? 4 : NT;
    constexpr int NCC = TC * 16;
    constexpr int CLB = 4 * 16 * NCC * 4;                       // Cl bytes
    constexpr int SMB = (MODE == 0 && 16384 > CLB) ? 16384 : CLB;
    // smem: MODE 0 = A half-tile (64x64 uints, swizzled) aliased with Cl; else Cl only
    __shared__ __align__(16) unsigned char smem[SMB];
    unsigned* As = (unsigned*)smem;
    __shared__ float scs[128], shs[128];
    const int tid = threadIdx.x;
    const int w = tid >> 6;
    const int lane = tid & 63;
    const int lane15 = lane & 15;
    const int quad = lane >> 4;
    const int row0 = gb * 64;
    const int m = row0 + w * 16 + lane15;
    const int mc = (m < M) ? m : 0;

    if (MODE == 1) {
        if (tid < 128) {
            float s = 0.f, q = 0.f;
#pragma unroll
            for (int i = 0; i < NSHARD; ++i) {
                s += sum[i * 128 + tid];
                q += ss[i * 128 + tid];
            }
            const float inv = 1.f / (float)M;
            const float mu = s * inv;
            const float var = q * inv - mu * mu;
            const float sc = gam[tid] * rsqrtf(var + 1e-5f);
            scs[tid] = sc;
            shs[tid] = bet[tid] - mu * sc;
        }
        __syncthreads();
    }

    f32x4 acc[NT];
#pragma unroll
    for (int t = 0; t < NT; ++t) acc[t] = (f32x4){0.f, 0.f, 0.f, 0.f};

    if (MODE == 0) {
        // ---- split-K coalesced stage: 2 halves of 64 rows x 128 fp32 -> bf16x2 LDS ----
        const float* xb = (const float*)Av + (long)row0 * 256;
        const int rlim = M - row0;
        const int ml = w * 16 + lane15;
#pragma unroll
        for (int kh = 0; kh < 2; ++kh) {
            if (kh) __syncthreads();          // all waves done reading previous half
#pragma unroll
            for (int it = 0; it < 4; ++it) {
                const int o = it * 256 + tid;        // 0..1023
                const int r = o >> 4;                // local row 0..63
                const int cc = o & 15;               // 8-float chunk within half-row
                float4 v0 = make_float4(0.f, 0.f, 0.f, 0.f);
                float4 v1 = make_float4(0.f, 0.f, 0.f, 0.f);
                if (r < rlim) {
                    v0 = *(const float4*)&xb[r * 256 + kh * 128 + cc * 8];
                    v1 = *(const float4*)&xb[r * 256 + kh * 128 + cc * 8 + 4];
                }
                *(uint4*)&As[r * 64 + ((cc * 4) ^ ((r & 7) << 2))] =
                    make_uint4(pack2(v0.x, v0.y), pack2(v0.z, v0.w),
                               pack2(v1.x, v1.y), pack2(v1.z, v1.w));
            }
            __syncthreads();
#pragma unroll
            for (int ks4 = 0; ks4 < 4; ++ks4) {
                const int ks = kh * 4 + ks4;
                const bf16x8 af = *(const bf16x8*)&As[ml * 64 + ((ks4 * 16 + quad * 4) ^ ((ml & 7) << 2))];
#pragma unroll
                for (int t = 0; t < NT; ++t) {
                    const bf16x8 bf = *(const bf16x8*)&Bp[(((ks * NT + t) * 64) + lane) * 8];
                    acc[t] = __builtin_amdgcn_mfma_f32_16x16x32_bf16(af, bf, acc[t], 0, 0, 0);
                }
            }
        }
        __syncthreads();   // hand-off: As region reused as Cl below
    } else {
        const unsigned* arow = (const unsigned*)Av + (long)mc * 64;
#pragma unroll
        for (int ks = 0; ks < 4; ++ks) {
            const uint4 pv = *(const uint4*)&arow[ks * 16 + quad * 4];
            const bf16x8 apre = u4_to_b8(pv.x, pv.y, pv.z, pv.w);
            const int c0 = ks * 32 + quad * 8;
            const float4 s0 = *(const float4*)&scs[c0];
            const float4 s1 = *(const float4*)&scs[c0 + 4];
            const float4 h0 = *(const float4*)&shs[c0];
            const float4 h1 = *(const float4*)&shs[c0 + 4];
            const bf16x8 aact = u4_to_b8(
                pack2(fmaxf(fmaf(blo(pv.x), s0.x, h0.x), 0.f), fmaxf(fmaf(bhi(pv.x), s0.y, h0.y), 0.f)),
                pack2(fmaxf(fmaf(blo(pv.y), s0.z, h0.z), 0.f), fmaxf(fmaf(bhi(pv.y), s0.w, h0.w), 0.f)),
                pack2(fmaxf(fmaf(blo(pv.z), s1.x, h1.x), 0.f), fmaxf(fmaf(bhi(pv.z), s1.y, h1.y), 0.f)),
                pack2(fmaxf(fmaf(blo(pv.w), s1.z, h1.z), 0.f), fmaxf(fmaf(bhi(pv.w), s1.w, h1.w), 0.f)));
#pragma unroll
            for (int t = 0; t < NT; ++t) {
                const bf16x8 bf = *(const bf16x8*)&Bp[(((ks * NT + t) * 64) + lane) * 8];
                acc[t] = __builtin_amdgcn_mfma_f32_16x16x32_bf16(aact, bf, acc[t], 0, 0, 0);
            }
#pragma unroll
            for (int t = 0; t < NT; ++t) {
                const bf16x8 bf = *(const bf16x8*)&Bp[((((ks + 4) * NT + t) * 64) + lane) * 8];
                acc[t] = __builtin_amdgcn_mfma_f32_16x16x32_bf16(apre, bf, acc[t], 0, 0, 0);
            }
        }
    }

    // per-wave chunked epilogue: LDS transpose -> pack -> vector stores
    float* cl = (float*)smem + w * 16 * NCC;
#pragma unroll
    for (int t0 = 0; t0 < NT; t0 += TC) {
#pragma unroll
        for (int tt = 0; tt < TC; ++tt)
#pragma unroll
            for (int r = 0; r < 4; ++r)
                cl[(quad * 4 + r) * NCC + tt * 16 + lane15] = acc[t0 + tt][r];
        if (FP8OUT) {
            constexpr int BPL = NCC / 4;     // fp8 bytes per lane
            const int f = lane * BPL;
            const int r = f / NCC;
            const int col = f % NCC;
            const int grow = row0 + w * 16 + r;
            unsigned ou[BPL / 4];
#pragma unroll
            for (int q = 0; q < BPL / 4; ++q) {
                const float4 v = *(const float4*)&cl[f + q * 4];
                ou[q] = pk_fp8x4(v.x, v.y, v.z, v.w);
            }
            if (grow < M) {
                unsigned char* cp = (unsigned char*)Cv + (long)grow * (NT * 16) + t0 * 16 + col;
                if (BPL == 16) *(uint4*)cp = make_uint4(ou[0], ou[1], ou[2], ou[3]);
                else           *(uint2*)cp = make_uint2(ou[0], ou[1]);
            }
        } else {
#pragma unroll
            for (int i = 0; i < (16 * NCC) / 512; ++i) {
                const int f = i * 512 + lane * 8;
                const int r = f / NCC;
                const int col = f % NCC;
                const int grow = row0 + w * 16 + r;
                const float4 lo = *(const float4*)&cl[f];
                const float4 hi = *(const float4*)&cl[f + 4];
                uint4 o;
                o.x = pack2(lo.x, lo.y);
                o.y = pack2(lo.z, lo.w);
                o.z = pack2(hi.x, hi.y);
                o.w = pack2(hi.z, hi.w);
                if (grow < M) *(uint4*)((short*)Cv + (long)grow * (NT * 16) + t0 * 16 + col) = o;
            }
        }
    }
}

// phase2 body: per bucket (staged at b*BCAP, count bcnt[b]): count -> scan -> rs + compact pe
__device__ __forceinline__ void phase2_body(
    int b, const unsigned* __restrict__ ebA, const unsigned char* __restrict__ ebB,
    const int* __restrict__ bcnt, int* __restrict__ rs, unsigned* __restrict__ pe)
{
    __shared__ int bscan[256];
    __shared__ int cnt[256];
    __shared__ int cur[256];
    const int t = threadIdx.x;
    const int v0 = (t < NBUCK) ? bcnt[t] : 0;
    bscan[t] = v0;
    __syncthreads();
    for (int off = 1; off < 256; off <<= 1) {
        const int x = (t >= off) ? bscan[t - off] : 0;
        __syncthreads();
        bscan[t] += x;
        __syncthreads();
    }
    const int nb = bcnt[b];
    const int e1 = bscan[b];      // compact end
    const int e0 = e1 - nb;       // compact start
    const int i0 = b * BCAP;      // staged start
    cnt[t] = 0;
    __syncthreads();
    for (int i = t; i < nb; i += 256) atomicAdd(&cnt[ebB[i0 + i]], 1);
    __syncthreads();
    const int v = cnt[t];
    __syncthreads();
    for (int off = 1; off < 256; off <<= 1) {
        const int x = (t >= off) ? cnt[t - off] : 0;
        __syncthreads();
        cnt[t] += x;
        __syncthreads();
    }
    const int exc = cnt[t] - v;
    const int node = b * 256 + t;
    if (node < NN) rs[node] = e0 + exc;
    if (b == 0 && t == 0) rs[NN] = NE;
    cur[t] = e0 + exc;
    __syncthreads();
    for (int i = t; i < nb; i += 256) {
        const int e = i0 + i;
        const int pos = atomicAdd(&cur[ebB[e]], 1);
        pe[pos] = ebA[e];
    }
}

// L2: phase2 (independent of GEMM, hidden under it) + layer-0 GEMM + W1/W2 packing
__global__ __launch_bounds__(256) void gemm0_p2(
    const float* __restrict__ x, const short* __restrict__ Bp, unsigned char* __restrict__ C, int M,
    const unsigned* __restrict__ ebA, const unsigned char* __restrict__ ebB,
    const int* __restrict__ bcnt, int* __restrict__ rs, unsigned* __restrict__ pe,
    const float* __restrict__ W1, const float* __restrict__ W2,
    short* __restrict__ Bp1, short* __restrict__ Bp2)
{
    if (blockIdx.x < NBUCK) {
        phase2_body(blockIdx.x, ebA, ebB, bcnt, rs, pe);
    } else if (blockIdx.x < NBUCK + GB0) {
        gemm_body<8, 0, true>(x, Bp, C, M, blockIdx.x - NBUCK, nullptr, nullptr, nullptr, nullptr);
    } else if (blockIdx.x < NBUCK + GB0 + 128) {
        packb_body(W1, Bp1, 8, blockIdx.x - (NBUCK + GB0));
    } else {
        packb_body(W2, Bp2, 2, blockIdx.x - (NBUCK + GB0 + 128));
    }
}

template <int NT, bool F8>
__global__ __launch_bounds__(256) void gemm_bn(
    const unsigned* __restrict__ A, const short* __restrict__ Bp, void* __restrict__ C, int M,
    const float* __restrict__ sum, const float* __restrict__ ss,
    const float* __restrict__ gam, const float* __restrict__ bet)
{
    gemm_body<NT, 1, F8>(A, Bp, C, M, blockIdx.x, sum, ss, gam, bet);
}

// ================= aggregation (layers 0 and 1): fp8 h rows (128 B) + fused BN stats =================
// 16 lanes/node, uint2 gathers (2x MLP vs 32-lane/4B); 16 nodes/block; lane handles 8 channels.
// Per-channel accumulation order identical to the 32-lane version (4-slot rotation, pairwise sum).
__global__ __launch_bounds__(256) void agg128f8(
    const unsigned* __restrict__ h4, const int* __restrict__ rs,
    const unsigned* __restrict__ pe, unsigned* __restrict__ outp,
    float* __restrict__ sumP, float* __restrict__ ssP)
{
    __shared__ float SL[2048];   // 16 nodes x 128 channels
    const int node = blockIdx.x * 16 + (threadIdx.x >> 4);
    const int l = threadIdx.x & 15;
    int j = rs[node];
    const int j1 = rs[node + 1];
    const uint2* hp = (const uint2*)h4;   // rows of 16 uint2 (128 B)
    float a[8][4];
#pragma unroll
    for (int c = 0; c < 8; ++c)
#pragma unroll
        for (int s = 0; s < 4; ++s) a[c][s] = 0.f;
    for (; j + 7 < j1; j += 8) {
        unsigned u[8]; uint2 v[8];
#pragma unroll
        for (int t = 0; t < 8; ++t) u[t] = pe[j + t];
#pragma unroll
        for (int t = 0; t < 8; ++t) v[t] = hp[(long)(u[t] & 0xFFFFu) * 16 + l];
#pragma unroll
        for (int t = 0; t < 8; ++t) {
            const float w = edgew(u[t]);
            const int s = t & 3;
            const f32x2 lo0 = __builtin_amdgcn_cvt_pk_f32_fp8((int)v[t].x, false);
            const f32x2 hi0 = __builtin_amdgcn_cvt_pk_f32_fp8((int)v[t].x, true);
            const f32x2 lo1 = __builtin_amdgcn_cvt_pk_f32_fp8((int)v[t].y, false);
            const f32x2 hi1 = __builtin_amdgcn_cvt_pk_f32_fp8((int)v[t].y, true);
            a[0][s] = fmaf(w, lo0.x, a[0][s]);
            a[1][s] = fmaf(w, lo0.y, a[1][s]);
            a[2][s] = fmaf(w, hi0.x, a[2][s]);
            a[3][s] = fmaf(w, hi0.y, a[3][s]);
            a[4][s] = fmaf(w, lo1.x, a[4][s]);
            a[5][s] = fmaf(w, lo1.y, a[5][s]);
            a[6][s] = fmaf(w, hi1.x, a[6][s]);
            a[7][s] = fmaf(w, hi1.y, a[7][s]);
        }
    }
    for (; j < j1; ++j) {
        const unsigned u = pe[j];
        const uint2 v = hp[(long)(u & 0xFFFFu) * 16 + l];
        const float w = edgew(u);
        const f32x2 lo0 = __builtin_amdgcn_cvt_pk_f32_fp8((int)v.x, false);
        const f32x2 hi0 = __builtin_amdgcn_cvt_pk_f32_fp8((int)v.x, true);
        const f32x2 lo1 = __builtin_amdgcn_cvt_pk_f32_fp8((int)v.y, false);
        const f32x2 hi1 = __builtin_amdgcn_cvt_pk_f32_fp8((int)v.y, true);
        a[0][0] = fmaf(w, lo0.x, a[0][0]);
        a[1][0] = fmaf(w, lo0.y, a[1][0]);
        a[2][0] = fmaf(w, hi0.x, a[2][0]);
        a[3][0] = fmaf(w, hi0.y, a[3][0]);
        a[4][0] = fmaf(w, lo1.x, a[4][0]);
        a[5][0] = fmaf(w, lo1.y, a[5][0]);
        a[6][0] = fmaf(w, hi1.x, a[6][0]);
        a[7][0] = fmaf(w, hi1.y, a[7][0]);
    }
    float c[8];
#pragma unroll
    for (int k = 0; k < 8; ++k) c[k] = (a[k][0] + a[k][1]) + (a[k][2] + a[k][3]);
    uint4 o;
    o.x = pack2(c[0], c[1]);
    o.y = pack2(c[2], c[3]);
    o.z = pack2(c[4], c[5]);
    o.w = pack2(c[6], c[7]);
    ((uint4*)outp)[(long)node * 16 + l] = o;

    // BN-stat epilogue: LDS-reduce the 16 nodes, sharded atomicAdd
    const int slot = threadIdx.x >> 4;
    *(float4*)&SL[slot * 128 + l * 8]     = make_float4(c[0], c[1], c[2], c[3]);
    *(float4*)&SL[slot * 128 + l * 8 + 4] = make_float4(c[4], c[5], c[6], c[7]);
    __syncthreads();
    if (threadIdx.x < 128) {
        float s = 0.f, q = 0.f;
#pragma unroll
        for (int i = 0; i < 16; ++i) {
            const float x = SL[i * 128 + threadIdx.x];
            s += x;
            q = fmaf(x, x, q);
        }
        const int sh = (blockIdx.x & (NSHARD - 1)) * 128 + threadIdx.x;
        atomicAdd(&sumP[sh], s);
        atomicAdd(&ssP[sh], q);
    }
}

// 8 lanes/node, uint2 gathers (bf16 h rows of 32), float4 fp32 output [NN,32]
__global__ __launch_bounds__(256) void agg32b(
    const unsigned* __restrict__ h2, const int* __restrict__ rs,
    const unsigned* __restrict__ pe, float* __restrict__ out)
{
    const int node = blockIdx.x * 32 + (threadIdx.x >> 3);
    if (node >= NN) return;
    const int l = threadIdx.x & 7;
    int j = rs[node];
    const int j1 = rs[node + 1];
    const uint2* hp = (const uint2*)h2;   // rows of 8 uint2
    float xa[4], ya[4], xb[4], yb[4];
#pragma unroll
    for (int t = 0; t < 4; ++t) { xa[t] = 0.f; ya[t] = 0.f; xb[t] = 0.f; yb[t] = 0.f; }
    for (; j + 7 < j1; j += 8) {
        unsigned u[8]; uint2 v[8];
#pragma unroll
        for (int t = 0; t < 8; ++t) u[t] = pe[j + t];
#pragma unroll
        for (int t = 0; t < 8; ++t) v[t] = hp[(long)(u[t] & 0xFFFFu) * 8 + l];
#pragma unroll
        for (int t = 0; t < 8; ++t) {
            const float w = edgew(u[t]);
            xa[t & 3] = fmaf(w, blo(v[t].x), xa[t & 3]);
            ya[t & 3] = fmaf(w, bhi(v[t].x), ya[t & 3]);
            xb[t & 3] = fmaf(w, blo(v[t].y), xb[t & 3]);
            yb[t & 3] = fmaf(w, bhi(v[t].y), yb[t & 3]);
        }
    }
    for (; j < j1; ++j) {
        const unsigned u = pe[j];
        const uint2 v = hp[(long)(u & 0xFFFFu) * 8 + l];
        const float w = edgew(u);
        xa[0] = fmaf(w, blo(v.x), xa[0]); ya[0] = fmaf(w, bhi(v.x), ya[0]);
        xb[0] = fmaf(w, blo(v.y), xb[0]); yb[0] = fmaf(w, bhi(v.y), yb[0]);
    }
    float4 o;
    o.x = (xa[0] + xa[1]) + (xa[2] + xa[3]);
    o.y = (ya[0] + ya[1]) + (ya[2] + ya[3]);
    o.z = (xb[0] + xb[1]) + (xb[2] + xb[3]);
    o.w = (yb[0] + yb[1]) + (yb[2] + yb[3]);
    ((float4*)out)[(long)node * 8 + l] = o;
}

extern "C" void kernel_launch(void* const* d_in, const int* in_sizes, int n_in,
                              void* d_out, int out_size, void* d_ws, size_t ws_size,
                              hipStream_t stream) {
    const float* x   = (const float*)d_in[0];
    const int*   src = (const int*)d_in[1];
    const int*   dst = (const int*)d_in[2];
    const float* ew  = (const float*)d_in[3];
    const float* W0  = (const float*)d_in[4];
    const float* W1  = (const float*)d_in[5];
    const float* W2  = (const float*)d_in[6];
    const float* g0  = (const float*)d_in[7];
    const float* b0  = (const float*)d_in[8];
    const float* g1  = (const float*)d_in[9];
    const float* b1  = (const float*)d_in[10];
    float* out = (float*)d_out;

    // workspace layout (h sized for bf16 [NN,128]; fp8 layers 0/1 alias the front)
    short* h   = (short*)d_ws;                         // fp8 [NN*128] bytes (L0,L1) / bf16 [NN*32] (L2)
    unsigned* x1p = (unsigned*)(h + (size_t)NN * 128); // [NN*64] uints = pre-only bf16x2
    float* st  = (float*)(x1p + (size_t)NN * 64);      // 8448 floats: stat shards + bucket ctrs
    int*  rs   = (int*)(st + 8448);                    // 50004
    unsigned* ebA = (unsigned*)(rs + 50004);           // NBUCK*BCAP staged src|w
    unsigned char* ebB = (unsigned char*)(ebA + NBUCK * BCAP); // NBUCK*BCAP dst low bytes
    unsigned* pe = (unsigned*)(ebB + NBUCK * BCAP);    // NE final packed edges
    short* Bp0 = (short*)(pe + NE);                    // 32768
    short* Bp1 = Bp0 + 32768;                          // 32768
    short* Bp2 = Bp1 + 32768;                          // 8192

    float* sum0P = st;                                 // [NSHARD][128]
    float* ss0P  = st + 2048;
    float* sum1P = st + 4096;
    float* ss1P  = st + 6144;
    int*   bcnt  = (int*)(st + 8192);                  // 256 bucket counters

    // zero stat shards & bucket counters (must complete before scatter's atomics)
    hipMemsetAsync(st, 0, 8448 * 4, stream);

    // L1: edge scatter into bucket staging + W0 pack
    scat_packb0_k<<<NBLK1 + 128, 256, 0, stream>>>(src, dst, ew, bcnt, ebA, ebB, W0, Bp0);

    // L2: phase2 (hidden under GEMM) + layer-0 GEMM (fp8 h) + W1/W2 packing
    gemm0_p2<<<NBUCK + GB0 + 160, 256, 0, stream>>>(x, Bp0, (unsigned char*)h, NN,
                                                    ebA, ebB, bcnt, rs, pe,
                                                    W1, W2, Bp1, Bp2);

    // ---- layer 0 aggregation (fp8 gathers, 16 lanes/node uint2) + fused BN stats ----
    agg128f8<<<3125, 256, 0, stream>>>((const unsigned*)h, rs, pe, x1p, sum0P, ss0P);

    // ---- layer 1 (BN0+ReLU fused into fragment load; fp8 h out) ----
    gemm_bn<8, true><<<782, 256, 0, stream>>>(x1p, Bp1, h, NN, sum0P, ss0P, g0, b0);
    agg128f8<<<3125, 256, 0, stream>>>((const unsigned*)h, rs, pe, x1p, sum1P, ss1P);

    // ---- output layer (bf16 h out) ----
    gemm_bn<2, false><<<782, 256, 0, stream>>>(x1p, Bp2, h, NN, sum1P, ss1P, g1, b1);
    agg32b<<<1563, 256, 0, stream>>>((const unsigned*)h, rs, pe, out);
}